// Round 11
// baseline (342.923 us; speedup 1.0000x reference)
//
#include <hip/hip_runtime.h>

#define D 512
typedef unsigned short ushort_t;
typedef __attribute__((ext_vector_type(8))) short bf16x8;
typedef __attribute__((ext_vector_type(4))) float f32x4;

static __device__ __forceinline__ ushort_t f2bf(float f) {
  unsigned u = __float_as_uint(f);
  u += 0x7fffu + ((u >> 16) & 1u);  // RNE
  return (ushort_t)(u >> 16);
}
static __device__ __forceinline__ float bf2f(ushort_t h) {
  return __uint_as_float(((unsigned)h) << 16);
}

static __device__ __forceinline__ void gld_lds16(const void* g, void* lds) {
  __builtin_amdgcn_global_load_lds(
      (const __attribute__((address_space(1))) unsigned int*)g,
      (__attribute__((address_space(3))) unsigned int*)lds, 16, 0, 0);
}

// ---------- weight pack: nmat x W[K][N] fp32 -> fragment-ready bf16 ----------
__global__ __launch_bounds__(256) void pack_weight(
    const float* __restrict__ W, ushort_t* __restrict__ out, int K, int N, int nmat) {
  int i = blockIdx.x * 256 + threadIdx.x;
  const int per = K * N;
  if (i >= per * nmat) return;
  const int mat = i / per;
  const int r = i - mat * per;
  const int k = r / N, n = r - k * N;
  const int nt = n >> 4, col = n & 15, kt = k >> 5, kg = (k >> 3) & 3, j = k & 7;
  out[(size_t)mat * per + (((size_t)nt * (K >> 5) + kt) << 9) + ((kg << 4) + col) * 8 + j] =
      f2bf(W[(size_t)mat * per + r]);
}

// ---------- fp32 -> bf16 row-major with row padding ----------
__global__ __launch_bounds__(256) void conv_bf16_pad(
    const float* __restrict__ in, ushort_t* __restrict__ out, int M, int Mp, int K) {
  const size_t i4 = ((size_t)blockIdx.x * 256 + threadIdx.x) * 4;
  if (i4 >= (size_t)Mp * K) return;
  const int row = (int)(i4 / K);
  ushort4 o;
  if (row < M) {
    const float4 v = *reinterpret_cast<const float4*>(&in[i4]);
    o.x = f2bf(v.x); o.y = f2bf(v.y); o.z = f2bf(v.z); o.w = f2bf(v.w);
  } else {
    o.x = o.y = o.z = o.w = 0;
  }
  *reinterpret_cast<ushort4*>(&out[i4]) = o;
}

// ---------- node MFMA GEMM: 128x128 tile, 8 waves (4x2), 2-phase dbuf -------
// optional fused attention dots: per-64-col-band partials, atomic-free.
__global__ __launch_bounds__(512) void gemm_mfma(
    const ushort_t* __restrict__ A, const ushort_t* __restrict__ Bp,
    const float* __restrict__ bias, ushort_t* __restrict__ C16,
    const float* __restrict__ watt, float* __restrict__ sd_part,
    float* __restrict__ ss_part, int Mp, int N, int K) {
  __shared__ __align__(16) ushort_t As[2][8 * 512];
  __shared__ __align__(16) ushort_t Bs[2][8 * 512];
  const int nwg = gridDim.x;
  const int q = nwg >> 3, rm = nwg & 7;
  const int xcd = blockIdx.x & 7, kk = blockIdx.x >> 3;
  const int lin = (xcd < rm ? xcd * (q + 1) : rm * (q + 1) + (xcd - rm) * q) + kk;
  const int m0 = (lin >> 2) * 128;
  const int n0 = (lin & 3) * 128;
  const int tid = threadIdx.x;
  const int lane = tid & 63;
  const int wid = tid >> 6;        // 0..7
  const int wm = wid >> 1;         // 0..3 (32-row band)
  const int wn = wid & 1;          // 0..1 (64-col band)
  const int arow = lane & 15;
  const int akoff = (lane >> 4) * 8;
  const int c15 = lane & 15;
  const int rgrp = lane >> 4;
  const int kt32 = K >> 5;
  f32x4 acc[2][4] = {};

  auto stage = [&](int kt, int b) {  // 2 gld per wave
    const int k0 = kt * 32;
    gld_lds16(&A[(size_t)(m0 + wid * 16 + arow) * K + k0 + akoff],
              &As[b][wid * 512]);
    gld_lds16(&Bp[(((size_t)(n0 / 16 + wid) * kt32 + kt) << 9) + lane * 8],
              &Bs[b][wid * 512]);
  };

  stage(0, 0);
  __syncthreads();
  int cur = 0;
  for (int t = 0; t < kt32; ++t) {
    if (t + 1 < kt32) stage(t + 1, cur ^ 1);
    bf16x8 af[2], bfr[4];
#pragma unroll
    for (int mi = 0; mi < 2; ++mi)
      af[mi] = *reinterpret_cast<const bf16x8*>(&As[cur][(wm * 2 + mi) * 512 + lane * 8]);
#pragma unroll
    for (int ni = 0; ni < 4; ++ni)
      bfr[ni] = *reinterpret_cast<const bf16x8*>(&Bs[cur][(wn * 4 + ni) * 512 + lane * 8]);
#pragma unroll
    for (int mi = 0; mi < 2; ++mi)
#pragma unroll
      for (int ni = 0; ni < 4; ++ni)
        acc[mi][ni] = __builtin_amdgcn_mfma_f32_16x16x32_bf16(af[mi], bfr[ni], acc[mi][ni], 0, 0, 0);
    __syncthreads();
    cur ^= 1;
  }
  const int band = (n0 >> 6) + wn;  // 0..7 (64-col bands)
#pragma unroll
  for (int mi = 0; mi < 2; ++mi) {
    const int row = m0 + wm * 32 + mi * 16 + (rgrp << 2);
#pragma unroll
    for (int r = 0; r < 4; ++r) {
      float psd = 0.f, pss = 0.f;
#pragma unroll
      for (int ni = 0; ni < 4; ++ni) {
        const int col = n0 + wn * 64 + ni * 16 + c15;
        const float v = acc[mi][ni][r] + bias[col];
        C16[(size_t)(row + r) * N + col] = f2bf(v);
        if (watt) {
          psd += v * watt[col];
          pss += v * watt[D + col];
        }
      }
      if (watt) {
#pragma unroll
        for (int off = 8; off > 0; off >>= 1) {
          psd += __shfl_xor(psd, off);
          pss += __shfl_xor(pss, off);
        }
        if (c15 == 0) {
          sd_part[(size_t)band * Mp + row + r] = psd;
          ss_part[(size_t)band * Mp + row + r] = pss;
        }
      }
    }
  }
}

// ---------- combine per-band dot partials ----------
__global__ __launch_bounds__(256) void combine_dots(
    const float* __restrict__ sd_part, const float* __restrict__ ss_part,
    float* __restrict__ sd, float* __restrict__ ss, int Mp, int Nn) {
  const int i = blockIdx.x * 256 + threadIdx.x;
  if (i >= Nn) return;
  float a = 0.f, b = 0.f;
#pragma unroll
  for (int bnd = 0; bnd < 8; ++bnd) {
    a += sd_part[(size_t)bnd * Mp + i];
    b += ss_part[(size_t)bnd * Mp + i];
  }
  sd[i] = a;
  ss[i] = b;
}

// ---------- bucket build: both hops, cap 64 per dst ----------
__global__ void fill_bucket(const int* __restrict__ e1, const int* __restrict__ e0,
                            int* __restrict__ cnt, int* __restrict__ bucket,
                            int Nn, int E) {
  const int e = blockIdx.x * blockDim.x + threadIdx.x;
  if (e >= E) return;
  const int d1 = e1[e];
  const int p1 = atomicAdd(&cnt[d1], 1);
  if (p1 < 64) bucket[(size_t)d1 * 64 + p1] = e1[E + e];
  const int d0 = e0[e];
  const int p0 = atomicAdd(&cnt[Nn + d0], 1);
  if (p0 < 64) bucket[((size_t)(Nn + d0)) * 64 + p0] = e0[E + e];
}

// ---------- GAT softmax + aggregate: 1 wave/dst, bf16x8, 4x unroll ----------
__global__ __launch_bounds__(256) void gat_aggregate_w(
    ushort_t* __restrict__ featb, const ushort_t* __restrict__ hb,
    const float* __restrict__ sd, const float* __restrict__ ss,
    const int* __restrict__ di, const int* __restrict__ si,
    const float* __restrict__ b_att_p, const float* __restrict__ gat_bias,
    const int* __restrict__ cnt, const int* __restrict__ bucket, int Nn, int E) {
  const int dst = blockIdx.x * 4 + (threadIdx.x >> 6);
  const int lane = threadIdx.x & 63;
  if (dst >= Nn) return;
  const int deg = cnt[dst];
  const float sdd = sd[dst];
  const float ba = b_att_p[0];
  const size_t o = (size_t)dst * D + lane * 8;
  bf16x8 fv = *reinterpret_cast<const bf16x8*>(&featb[o]);  // hoisted RMW load
  float acc[8] = {};
  if (deg <= 64) {
    const bool valid = lane < deg;
    const int slane = valid ? bucket[(size_t)dst * 64 + lane] : 0;
    const float e = valid ? tanhf(sdd + ss[slane] + ba) : -1e30f;
    float m = e;
#pragma unroll
    for (int off = 32; off > 0; off >>= 1) m = fmaxf(m, __shfl_xor(m, off));
    const float a = valid ? expf(e - m) : 0.f;
    float s = a;
#pragma unroll
    for (int off = 32; off > 0; off >>= 1) s += __shfl_xor(s, off);
    const float w = a * ((s > 0.f) ? 1.f / s : 0.f);  // per-lane alpha
    int k = 0;
    for (; k + 3 < deg; k += 4) {
      const float w0 = __shfl(w, k), w1 = __shfl(w, k + 1);
      const float w2 = __shfl(w, k + 2), w3 = __shfl(w, k + 3);
      const int s0 = __shfl(slane, k), s1 = __shfl(slane, k + 1);
      const int s2 = __shfl(slane, k + 2), s3 = __shfl(slane, k + 3);
      const bf16x8 h0 = *reinterpret_cast<const bf16x8*>(&hb[(size_t)s0 * D + lane * 8]);
      const bf16x8 h1 = *reinterpret_cast<const bf16x8*>(&hb[(size_t)s1 * D + lane * 8]);
      const bf16x8 h2 = *reinterpret_cast<const bf16x8*>(&hb[(size_t)s2 * D + lane * 8]);
      const bf16x8 h3 = *reinterpret_cast<const bf16x8*>(&hb[(size_t)s3 * D + lane * 8]);
#pragma unroll
      for (int qq = 0; qq < 8; ++qq) {
        const float t0 = w0 * bf2f((ushort_t)h0[qq]) + w1 * bf2f((ushort_t)h1[qq]);
        const float t1 = w2 * bf2f((ushort_t)h2[qq]) + w3 * bf2f((ushort_t)h3[qq]);
        acc[qq] += t0 + t1;
      }
    }
    for (; k < deg; ++k) {
      const float wk = __shfl(w, k);
      const int sk = __shfl(slane, k);
      const bf16x8 h0 = *reinterpret_cast<const bf16x8*>(&hb[(size_t)sk * D + lane * 8]);
#pragma unroll
      for (int qq = 0; qq < 8; ++qq) acc[qq] += wk * bf2f((ushort_t)h0[qq]);
    }
  } else {
    // overflow fallback (deg > 64): ballot-scan the raw edge list. Correct for
    // any degree; effectively never taken for this graph.
    float m = -1e30f;
    for (int e = lane; e < E; e += 64)
      if (di[e] == dst) m = fmaxf(m, tanhf(sdd + ss[si[e]] + ba));
#pragma unroll
    for (int off = 32; off > 0; off >>= 1) m = fmaxf(m, __shfl_xor(m, off));
    float s = 0.f;
    for (int e = lane; e < E; e += 64)
      if (di[e] == dst) s += expf(tanhf(sdd + ss[si[e]] + ba) - m);
#pragma unroll
    for (int off = 32; off > 0; off >>= 1) s += __shfl_xor(s, off);
    const float inv = (s > 0.f) ? 1.f / s : 0.f;
    for (int base = 0; base < E; base += 64) {
      const int e = base + lane;
      const bool hit = (e < E) && (di[e] == dst);
      unsigned long long mask = __ballot(hit);
      const int sidx = hit ? si[e] : 0;
      const float aval = hit ? expf(tanhf(sdd + ss[sidx] + ba) - m) * inv : 0.f;
      while (mask) {
        const int l = __ffsll((long long)mask) - 1;
        mask &= mask - 1;
        const float wv = __shfl(aval, l);
        const int sk = __shfl(sidx, l);
        const bf16x8 hv = *reinterpret_cast<const bf16x8*>(&hb[(size_t)sk * D + lane * 8]);
#pragma unroll
        for (int qq = 0; qq < 8; ++qq) acc[qq] += wv * bf2f((ushort_t)hv[qq]);
      }
    }
  }
#pragma unroll
  for (int q = 0; q < 8; ++q) {
    const float f = (bf2f((ushort_t)fv[q]) + acc[q] + gat_bias[lane * 8 + q]) * 0.5f;
    fv[q] = (short)f2bf(f);
  }
  *reinterpret_cast<bf16x8*>(&featb[o]) = fv;
}

// ---------- fused head: gather -> Wp -> 2x(2x(GEMM,tanh,LN), res LN) -> logit
__global__ __launch_bounds__(1024, 4) void head_fused(
    const ushort_t* __restrict__ featb, const int* __restrict__ tidx,
    const ushort_t* __restrict__ pWp, const float* __restrict__ bp,
    const ushort_t* __restrict__ pDW, const float* __restrict__ dnn_b,
    const float* __restrict__ dnn_g, const float* __restrict__ dnn_be,
    const float* __restrict__ res_g, const float* __restrict__ res_be,
    const float* __restrict__ Wc, const float* __restrict__ bc,
    float* __restrict__ out) {
  __shared__ __align__(16) ushort_t A_lds[16 * 512];
  __shared__ float lsum[16][16], lsq[16][16], meanv[16], rsv[16];
  const int tid = threadIdx.x;
  const int lane = tid & 63;
  const int wave = tid >> 6;      // 0..15
  const int nt0 = wave * 2;       // 2 n-tiles (32 cols) per wave
  const int c15 = lane & 15;
  const int rgrp = lane >> 4;

  {
    const int row = tid >> 6, col8 = tid & 63;
    const int g = tidx[blockIdx.x * 16 + row];
    const bf16x8 v = *reinterpret_cast<const bf16x8*>(&featb[(size_t)g * D + col8 * 8]);
    *reinterpret_cast<bf16x8*>(&A_lds[row * 512 + (col8 ^ (row & 7)) * 8]) = v;
  }
  __syncthreads();

  auto do_gemm = [&](const ushort_t* __restrict__ W, f32x4& a0, f32x4& a1) {
    a0 = f32x4{0.f, 0.f, 0.f, 0.f};
    a1 = f32x4{0.f, 0.f, 0.f, 0.f};
    bf16x8 c0 = *reinterpret_cast<const bf16x8*>(
        &W[(((size_t)nt0 * 16 + 0) << 9) + lane * 8]);
    bf16x8 c1 = *reinterpret_cast<const bf16x8*>(
        &W[(((size_t)(nt0 + 1) * 16 + 0) << 9) + lane * 8]);
#pragma unroll
    for (int kt = 0; kt < 16; ++kt) {
      bf16x8 n0 = c0, n1 = c1;
      if (kt < 15) {
        n0 = *reinterpret_cast<const bf16x8*>(
            &W[(((size_t)nt0 * 16 + kt + 1) << 9) + lane * 8]);
        n1 = *reinterpret_cast<const bf16x8*>(
            &W[(((size_t)(nt0 + 1) * 16 + kt + 1) << 9) + lane * 8]);
      }
      const int col8 = kt * 4 + rgrp;
      const bf16x8 af = *reinterpret_cast<const bf16x8*>(
          &A_lds[c15 * 512 + (col8 ^ (c15 & 7)) * 8]);
      a0 = __builtin_amdgcn_mfma_f32_16x16x32_bf16(af, c0, a0, 0, 0, 0);
      a1 = __builtin_amdgcn_mfma_f32_16x16x32_bf16(af, c1, a1, 0, 0, 0);
      c0 = n0;
      c1 = n1;
    }
  };

  auto block_ln = [&](f32x4& v0, f32x4& v1, const float* __restrict__ g,
                      const float* __restrict__ be) {
    float psum[4], psq[4];
#pragma unroll
    for (int r = 0; r < 4; ++r) {
      psum[r] = v0[r] + v1[r];
      psq[r] = v0[r] * v0[r] + v1[r] * v1[r];
    }
#pragma unroll
    for (int off = 8; off > 0; off >>= 1)
#pragma unroll
      for (int r = 0; r < 4; ++r) {
        psum[r] += __shfl_xor(psum[r], off);
        psq[r] += __shfl_xor(psq[r], off);
      }
    if (c15 == 0) {
#pragma unroll
      for (int r = 0; r < 4; ++r) {
        lsum[wave][rgrp * 4 + r] = psum[r];
        lsq[wave][rgrp * 4 + r] = psq[r];
      }
    }
    __syncthreads();
    if (tid < 16) {
      float s = 0.f, qq = 0.f;
#pragma unroll
      for (int w = 0; w < 16; ++w) { s += lsum[w][tid]; qq += lsq[w][tid]; }
      const float mean = s * (1.f / 512.f);
      const float var = qq * (1.f / 512.f) - mean * mean;
      meanv[tid] = mean;
      rsv[tid] = rsqrtf(var + 1e-5f);
    }
    __syncthreads();
    const int col0 = nt0 * 16 + c15;
    const int col1 = (nt0 + 1) * 16 + c15;
    const float g0 = g[col0], b0 = be[col0];
    const float g1 = g[col1], b1 = be[col1];
#pragma unroll
    for (int r = 0; r < 4; ++r) {
      const int row = rgrp * 4 + r;
      v0[r] = (v0[r] - meanv[row]) * rsv[row] * g0 + b0;
      v1[r] = (v1[r] - meanv[row]) * rsv[row] * g1 + b1;
    }
  };

  auto store_A = [&](const f32x4& v0, const f32x4& v1) {
    const int col0 = nt0 * 16 + c15;
    const int col1 = (nt0 + 1) * 16 + c15;
#pragma unroll
    for (int r = 0; r < 4; ++r) {
      const int row = rgrp * 4 + r;
      A_lds[row * 512 + (((col0 >> 3) ^ (row & 7)) << 3) + (col0 & 7)] = f2bf(v0[r]);
      A_lds[row * 512 + (((col1 >> 3) ^ (row & 7)) << 3) + (col1 & 7)] = f2bf(v1[r]);
    }
  };

  f32x4 sc0, sc1, acc0, acc1, ln0, ln1;

  do_gemm(pWp, acc0, acc1);
  {
    const float bv0 = bp[nt0 * 16 + c15];
    const float bv1 = bp[(nt0 + 1) * 16 + c15];
#pragma unroll
    for (int r = 0; r < 4; ++r) { sc0[r] = acc0[r] + bv0; sc1[r] = acc1[r] + bv1; }
  }
  __syncthreads();
  store_A(sc0, sc1);
  __syncthreads();

  for (int rb = 0; rb < 2; ++rb) {
    {
      const int st = rb * 2;
      do_gemm(pDW + (size_t)st * D * D, acc0, acc1);
      const float bv0 = dnn_b[st * D + nt0 * 16 + c15];
      const float bv1 = dnn_b[st * D + (nt0 + 1) * 16 + c15];
#pragma unroll
      for (int r = 0; r < 4; ++r) {
        acc0[r] = tanhf(acc0[r] + bv0);
        acc1[r] = tanhf(acc1[r] + bv1);
      }
      block_ln(acc0, acc1, dnn_g + st * D, dnn_be + st * D);
      store_A(acc0, acc1);
      __syncthreads();
    }
    {
      const int st = rb * 2 + 1;
      do_gemm(pDW + (size_t)st * D * D, ln0, ln1);
      const float bv0 = dnn_b[st * D + nt0 * 16 + c15];
      const float bv1 = dnn_b[st * D + (nt0 + 1) * 16 + c15];
#pragma unroll
      for (int r = 0; r < 4; ++r) {
        ln0[r] = tanhf(ln0[r] + bv0);
        ln1[r] = tanhf(ln1[r] + bv1);
      }
      block_ln(ln0, ln1, dnn_g + st * D, dnn_be + st * D);
    }
#pragma unroll
    for (int r = 0; r < 4; ++r) {
      acc0[r] = tanhf(sc0[r] + ln0[r]);
      acc1[r] = tanhf(sc1[r] + ln1[r]);
    }
    block_ln(acc0, acc1, res_g + rb * D, res_be + rb * D);
    sc0 = acc0;
    sc1 = acc1;
    if (rb == 0) {
      store_A(sc0, sc1);
      __syncthreads();
    }
  }

  float pr[4];
  {
    const float w0 = Wc[nt0 * 16 + c15];
    const float w1 = Wc[(nt0 + 1) * 16 + c15];
#pragma unroll
    for (int r = 0; r < 4; ++r) pr[r] = sc0[r] * w0 + sc1[r] * w1;
  }
#pragma unroll
  for (int off = 8; off > 0; off >>= 1)
#pragma unroll
    for (int r = 0; r < 4; ++r) pr[r] += __shfl_xor(pr[r], off);
  __syncthreads();
  if (c15 == 0) {
#pragma unroll
    for (int r = 0; r < 4; ++r) lsum[wave][rgrp * 4 + r] = pr[r];
  }
  __syncthreads();
  if (tid < 16) {
    float s = 0.f;
#pragma unroll
    for (int w = 0; w < 16; ++w) s += lsum[w][tid];
    out[blockIdx.x * 16 + tid] = 1.f / (1.f + expf(-(s + bc[0])));
  }
}

extern "C" void kernel_launch(void* const* d_in, const int* in_sizes, int n_in,
                              void* d_out, int out_size, void* d_ws, size_t ws_size,
                              hipStream_t stream) {
  (void)n_in; (void)out_size; (void)ws_size;
  const float* node_feat = (const float*)d_in[0];
  const int* edge0 = (const int*)d_in[1];
  const int* edge1 = (const int*)d_in[2];
  const int* tidx = (const int*)d_in[3];
  const float* Wt = (const float*)d_in[4];
  const float* bt = (const float*)d_in[5];
  const float* Wf = (const float*)d_in[6];
  const float* bfp = (const float*)d_in[7];
  const float* w_att = (const float*)d_in[8];
  const float* b_att = (const float*)d_in[9];
  const float* gat_bias = (const float*)d_in[10];
  const float* Wp = (const float*)d_in[11];
  const float* bp = (const float*)d_in[12];
  const float* dnn_W = (const float*)d_in[13];
  const float* dnn_b = (const float*)d_in[14];
  const float* dnn_g = (const float*)d_in[15];
  const float* dnn_be = (const float*)d_in[16];
  const float* res_g = (const float*)d_in[17];
  const float* res_be = (const float*)d_in[18];
  const float* Wc = (const float*)d_in[19];
  const float* bc = (const float*)d_in[20];
  float* out = (float*)d_out;

  const int Nn = in_sizes[0] / D;   // 30000
  const int E = in_sizes[1] / 2;    // 300000
  const int B = in_sizes[3];        // 4096
  const int K_IN = in_sizes[4] / D; // 512
  const int Mp = (Nn + 127) / 128 * 128;
  const int N2 = 2 * Nn;

  char* p = (char*)d_ws;
  auto alloc = [&](size_t bytes) -> char* {
    char* r = p;
    p += (bytes + 255) & ~(size_t)255;
    return r;
  };
  ushort_t* featb = (ushort_t*)alloc((size_t)Mp * D * 2);
  ushort_t* hb = (ushort_t*)alloc((size_t)Mp * D * 2);  // also nfb pre-hop
  float* sd = (float*)alloc((size_t)Nn * 4);
  float* ss = (float*)alloc((size_t)Nn * 4);
  float* sd_part = (float*)alloc((size_t)8 * Mp * 4);
  float* ss_part = (float*)alloc((size_t)8 * Mp * 4);
  int* cnt = (int*)alloc((size_t)N2 * 4);
  int* bucket = (int*)alloc((size_t)N2 * 64 * 4);
  ushort_t* pWt = (ushort_t*)alloc((size_t)K_IN * D * 2);
  ushort_t* pWf = (ushort_t*)alloc((size_t)D * D * 2);
  ushort_t* pWp = (ushort_t*)alloc((size_t)D * D * 2);
  ushort_t* pDWall = (ushort_t*)alloc((size_t)4 * D * D * 2);

  dim3 blk(256);
  const int nw4 = (Nn + 3) / 4;

  // ---- one-time packs / converts ----
  {
    pack_weight<<<(K_IN * D + 255) / 256, blk, 0, stream>>>(Wt, pWt, K_IN, D, 1);
    pack_weight<<<(D * D + 255) / 256, blk, 0, stream>>>(Wf, pWf, D, D, 1);
    pack_weight<<<(D * D + 255) / 256, blk, 0, stream>>>(Wp, pWp, D, D, 1);
    pack_weight<<<(4 * D * D + 255) / 256, blk, 0, stream>>>(dnn_W, pDWall, D, D, 4);
    conv_bf16_pad<<<((size_t)Mp * K_IN / 4 + 255) / 256, blk, 0, stream>>>(
        node_feat, hb /*nfb*/, Nn, Mp, K_IN);
  }

  // ---- bucket build for both hops (hop1 -> segment 0, hop0 -> segment 1) ----
  hipMemsetAsync(cnt, 0, (size_t)N2 * 4, stream);
  fill_bucket<<<(E + 255) / 256, blk, 0, stream>>>(edge1, edge0, cnt, bucket, Nn, E);

  // ---- feat = node_feat @ Wt + bt ----
  gemm_mfma<<<dim3(4 * (Mp / 128)), dim3(512), 0, stream>>>(
      hb, pWt, bt, featb, nullptr, nullptr, nullptr, Mp, D, K_IN);

  // ---- two GAT hops (h-GEMM with fused band-partial attention dots) ----
  const int* hops[2] = {edge1, edge0};
  for (int hp = 0; hp < 2; ++hp) {
    gemm_mfma<<<dim3(4 * (Mp / 128)), dim3(512), 0, stream>>>(
        featb, pWf, bfp, hb, w_att, sd_part, ss_part, Mp, D, D);
    combine_dots<<<(Nn + 255) / 256, blk, 0, stream>>>(sd_part, ss_part, sd, ss, Mp, Nn);
    gat_aggregate_w<<<nw4, blk, 0, stream>>>(
        featb, hb, sd, ss, hops[hp], hops[hp] + E, b_att, gat_bias,
        cnt + hp * Nn, bucket + (size_t)hp * Nn * 64, Nn, E);
  }

  // ---- fused head ----
  head_fused<<<B / 16, dim3(1024), 0, stream>>>(
      featb, tidx, pWp, bp, pDWall, dnn_b, dnn_g, dnn_be, res_g, res_be,
      Wc, bc, out);
}

// Round 12
// 317.186 us; speedup vs baseline: 1.0811x; 1.0811x over previous
//
#include <hip/hip_runtime.h>

#define D 512
typedef unsigned short ushort_t;
typedef __attribute__((ext_vector_type(8))) short bf16x8;
typedef __attribute__((ext_vector_type(4))) float f32x4;

static __device__ __forceinline__ ushort_t f2bf(float f) {
  unsigned u = __float_as_uint(f);
  u += 0x7fffu + ((u >> 16) & 1u);  // RNE
  return (ushort_t)(u >> 16);
}
static __device__ __forceinline__ float bf2f(ushort_t h) {
  return __uint_as_float(((unsigned)h) << 16);
}

static __device__ __forceinline__ void gld_lds16(const void* g, void* lds) {
  __builtin_amdgcn_global_load_lds(
      (const __attribute__((address_space(1))) unsigned int*)g,
      (__attribute__((address_space(3))) unsigned int*)lds, 16, 0, 0);
}

// ---------- weight pack: nmat x W[K][N] fp32 -> fragment-ready bf16 ----------
__global__ __launch_bounds__(256) void pack_weight(
    const float* __restrict__ W, ushort_t* __restrict__ out, int K, int N, int nmat) {
  int i = blockIdx.x * 256 + threadIdx.x;
  const int per = K * N;
  if (i >= per * nmat) return;
  const int mat = i / per;
  const int r = i - mat * per;
  const int k = r / N, n = r - k * N;
  const int nt = n >> 4, col = n & 15, kt = k >> 5, kg = (k >> 3) & 3, j = k & 7;
  out[(size_t)mat * per + (((size_t)nt * (K >> 5) + kt) << 9) + ((kg << 4) + col) * 8 + j] =
      f2bf(W[(size_t)mat * per + r]);
}

// ---------- fp32 -> bf16 row-major with row padding ----------
__global__ __launch_bounds__(256) void conv_bf16_pad(
    const float* __restrict__ in, ushort_t* __restrict__ out, int M, int Mp, int K) {
  const size_t i4 = ((size_t)blockIdx.x * 256 + threadIdx.x) * 4;
  if (i4 >= (size_t)Mp * K) return;
  const int row = (int)(i4 / K);
  ushort4 o;
  if (row < M) {
    const float4 v = *reinterpret_cast<const float4*>(&in[i4]);
    o.x = f2bf(v.x); o.y = f2bf(v.y); o.z = f2bf(v.z); o.w = f2bf(v.w);
  } else {
    o.x = o.y = o.z = o.w = 0;
  }
  *reinterpret_cast<ushort4*>(&out[i4]) = o;
}

// ---------- node MFMA GEMM: 128x128 tile, 8 waves (4x2), 2-phase dbuf -------
// optional fused attention dots: per-64-col-band partials, atomic-free.
__global__ __launch_bounds__(512) void gemm_mfma(
    const ushort_t* __restrict__ A, const ushort_t* __restrict__ Bp,
    const float* __restrict__ bias, ushort_t* __restrict__ C16,
    const float* __restrict__ watt, float* __restrict__ sd_part,
    float* __restrict__ ss_part, int Mp, int N, int K) {
  __shared__ __align__(16) ushort_t As[2][8 * 512];
  __shared__ __align__(16) ushort_t Bs[2][8 * 512];
  const int nwg = gridDim.x;
  const int q = nwg >> 3, rm = nwg & 7;
  const int xcd = blockIdx.x & 7, kk = blockIdx.x >> 3;
  const int lin = (xcd < rm ? xcd * (q + 1) : rm * (q + 1) + (xcd - rm) * q) + kk;
  const int m0 = (lin >> 2) * 128;
  const int n0 = (lin & 3) * 128;
  const int tid = threadIdx.x;
  const int lane = tid & 63;
  const int wid = tid >> 6;        // 0..7
  const int wm = wid >> 1;         // 0..3 (32-row band)
  const int wn = wid & 1;          // 0..1 (64-col band)
  const int arow = lane & 15;
  const int akoff = (lane >> 4) * 8;
  const int c15 = lane & 15;
  const int rgrp = lane >> 4;
  const int kt32 = K >> 5;
  f32x4 acc[2][4] = {};

  auto stage = [&](int kt, int b) {  // 2 gld per wave
    const int k0 = kt * 32;
    gld_lds16(&A[(size_t)(m0 + wid * 16 + arow) * K + k0 + akoff],
              &As[b][wid * 512]);
    gld_lds16(&Bp[(((size_t)(n0 / 16 + wid) * kt32 + kt) << 9) + lane * 8],
              &Bs[b][wid * 512]);
  };

  stage(0, 0);
  __syncthreads();
  int cur = 0;
  for (int t = 0; t < kt32; ++t) {
    if (t + 1 < kt32) stage(t + 1, cur ^ 1);
    bf16x8 af[2], bfr[4];
#pragma unroll
    for (int mi = 0; mi < 2; ++mi)
      af[mi] = *reinterpret_cast<const bf16x8*>(&As[cur][(wm * 2 + mi) * 512 + lane * 8]);
#pragma unroll
    for (int ni = 0; ni < 4; ++ni)
      bfr[ni] = *reinterpret_cast<const bf16x8*>(&Bs[cur][(wn * 4 + ni) * 512 + lane * 8]);
#pragma unroll
    for (int mi = 0; mi < 2; ++mi)
#pragma unroll
      for (int ni = 0; ni < 4; ++ni)
        acc[mi][ni] = __builtin_amdgcn_mfma_f32_16x16x32_bf16(af[mi], bfr[ni], acc[mi][ni], 0, 0, 0);
    __syncthreads();
    cur ^= 1;
  }
  const int band = (n0 >> 6) + wn;  // 0..7 (64-col bands)
#pragma unroll
  for (int mi = 0; mi < 2; ++mi) {
    const int row = m0 + wm * 32 + mi * 16 + (rgrp << 2);
#pragma unroll
    for (int r = 0; r < 4; ++r) {
      float psd = 0.f, pss = 0.f;
#pragma unroll
      for (int ni = 0; ni < 4; ++ni) {
        const int col = n0 + wn * 64 + ni * 16 + c15;
        const float v = acc[mi][ni][r] + bias[col];
        C16[(size_t)(row + r) * N + col] = f2bf(v);
        if (watt) {
          psd += v * watt[col];
          pss += v * watt[D + col];
        }
      }
      if (watt) {
#pragma unroll
        for (int off = 8; off > 0; off >>= 1) {
          psd += __shfl_xor(psd, off);
          pss += __shfl_xor(pss, off);
        }
        if (c15 == 0) {
          sd_part[(size_t)band * Mp + row + r] = psd;
          ss_part[(size_t)band * Mp + row + r] = pss;
        }
      }
    }
  }
}

// ---------- combine per-band dot partials ----------
__global__ __launch_bounds__(256) void combine_dots(
    const float* __restrict__ sd_part, const float* __restrict__ ss_part,
    float* __restrict__ sd, float* __restrict__ ss, int Mp, int Nn) {
  const int i = blockIdx.x * 256 + threadIdx.x;
  if (i >= Nn) return;
  float a = 0.f, b = 0.f;
#pragma unroll
  for (int bnd = 0; bnd < 8; ++bnd) {
    a += sd_part[(size_t)bnd * Mp + i];
    b += ss_part[(size_t)bnd * Mp + i];
  }
  sd[i] = a;
  ss[i] = b;
}

// ---------- bucket build: both hops, cap 64 per dst ----------
__global__ void fill_bucket(const int* __restrict__ e1, const int* __restrict__ e0,
                            int* __restrict__ cnt, int* __restrict__ bucket,
                            int Nn, int E) {
  const int e = blockIdx.x * blockDim.x + threadIdx.x;
  if (e >= E) return;
  const int d1 = e1[e];
  const int p1 = atomicAdd(&cnt[d1], 1);
  if (p1 < 64) bucket[(size_t)d1 * 64 + p1] = e1[E + e];
  const int d0 = e0[e];
  const int p0 = atomicAdd(&cnt[Nn + d0], 1);
  if (p0 < 64) bucket[((size_t)(Nn + d0)) * 64 + p0] = e0[E + e];
}

// ---------- target set: flag + compact ----------
__global__ void mark_targets(const int* __restrict__ tidx, int* __restrict__ flag, int B) {
  const int i = blockIdx.x * 256 + threadIdx.x;
  if (i < B) flag[tidx[i]] = 1;
}
__global__ void compact_targets(const int* __restrict__ flag, int* __restrict__ list,
                                int* __restrict__ count, int Nn) {
  const int i = blockIdx.x * 256 + threadIdx.x;
  if (i < Nn && flag[i]) list[atomicAdd(count, 1)] = i;
}

// ---------- GAT softmax + aggregate: 1 wave/dst, bf16x8, 4x unroll ----------
// optional dstlist: process only listed dst nodes (count read from device).
__global__ __launch_bounds__(256) void gat_aggregate_w(
    ushort_t* __restrict__ featb, const ushort_t* __restrict__ hb,
    const float* __restrict__ sd, const float* __restrict__ ss,
    const int* __restrict__ di, const int* __restrict__ si,
    const float* __restrict__ b_att_p, const float* __restrict__ gat_bias,
    const int* __restrict__ cnt, const int* __restrict__ bucket,
    const int* __restrict__ dstlist, const int* __restrict__ dcount,
    int Nn, int E) {
  const int gidx = blockIdx.x * 4 + (threadIdx.x >> 6);
  const int lane = threadIdx.x & 63;
  int dst;
  if (dstlist) {
    if (gidx >= *dcount) return;
    dst = dstlist[gidx];
  } else {
    if (gidx >= Nn) return;
    dst = gidx;
  }
  const int deg = cnt[dst];
  const float sdd = sd[dst];
  const float ba = b_att_p[0];
  const size_t o = (size_t)dst * D + lane * 8;
  bf16x8 fv = *reinterpret_cast<const bf16x8*>(&featb[o]);  // hoisted RMW load
  float acc[8] = {};
  if (deg <= 64) {
    const bool valid = lane < deg;
    const int slane = valid ? bucket[(size_t)dst * 64 + lane] : 0;
    const float e = valid ? tanhf(sdd + ss[slane] + ba) : -1e30f;
    float m = e;
#pragma unroll
    for (int off = 32; off > 0; off >>= 1) m = fmaxf(m, __shfl_xor(m, off));
    const float a = valid ? expf(e - m) : 0.f;
    float s = a;
#pragma unroll
    for (int off = 32; off > 0; off >>= 1) s += __shfl_xor(s, off);
    const float w = a * ((s > 0.f) ? 1.f / s : 0.f);  // per-lane alpha
    int k = 0;
    for (; k + 3 < deg; k += 4) {
      const float w0 = __shfl(w, k), w1 = __shfl(w, k + 1);
      const float w2 = __shfl(w, k + 2), w3 = __shfl(w, k + 3);
      const int s0 = __shfl(slane, k), s1 = __shfl(slane, k + 1);
      const int s2 = __shfl(slane, k + 2), s3 = __shfl(slane, k + 3);
      const bf16x8 h0 = *reinterpret_cast<const bf16x8*>(&hb[(size_t)s0 * D + lane * 8]);
      const bf16x8 h1 = *reinterpret_cast<const bf16x8*>(&hb[(size_t)s1 * D + lane * 8]);
      const bf16x8 h2 = *reinterpret_cast<const bf16x8*>(&hb[(size_t)s2 * D + lane * 8]);
      const bf16x8 h3 = *reinterpret_cast<const bf16x8*>(&hb[(size_t)s3 * D + lane * 8]);
#pragma unroll
      for (int qq = 0; qq < 8; ++qq) {
        const float t0 = w0 * bf2f((ushort_t)h0[qq]) + w1 * bf2f((ushort_t)h1[qq]);
        const float t1 = w2 * bf2f((ushort_t)h2[qq]) + w3 * bf2f((ushort_t)h3[qq]);
        acc[qq] += t0 + t1;
      }
    }
    for (; k < deg; ++k) {
      const float wk = __shfl(w, k);
      const int sk = __shfl(slane, k);
      const bf16x8 h0 = *reinterpret_cast<const bf16x8*>(&hb[(size_t)sk * D + lane * 8]);
#pragma unroll
      for (int qq = 0; qq < 8; ++qq) acc[qq] += wk * bf2f((ushort_t)h0[qq]);
    }
  } else {
    // overflow fallback (deg > 64): ballot-scan the raw edge list. Correct for
    // any degree; effectively never taken for this graph.
    float m = -1e30f;
    for (int e = lane; e < E; e += 64)
      if (di[e] == dst) m = fmaxf(m, tanhf(sdd + ss[si[e]] + ba));
#pragma unroll
    for (int off = 32; off > 0; off >>= 1) m = fmaxf(m, __shfl_xor(m, off));
    float s = 0.f;
    for (int e = lane; e < E; e += 64)
      if (di[e] == dst) s += expf(tanhf(sdd + ss[si[e]] + ba) - m);
#pragma unroll
    for (int off = 32; off > 0; off >>= 1) s += __shfl_xor(s, off);
    const float inv = (s > 0.f) ? 1.f / s : 0.f;
    for (int base = 0; base < E; base += 64) {
      const int e = base + lane;
      const bool hit = (e < E) && (di[e] == dst);
      unsigned long long mask = __ballot(hit);
      const int sidx = hit ? si[e] : 0;
      const float aval = hit ? expf(tanhf(sdd + ss[sidx] + ba) - m) * inv : 0.f;
      while (mask) {
        const int l = __ffsll((long long)mask) - 1;
        mask &= mask - 1;
        const float wv = __shfl(aval, l);
        const int sk = __shfl(sidx, l);
        const bf16x8 hv = *reinterpret_cast<const bf16x8*>(&hb[(size_t)sk * D + lane * 8]);
#pragma unroll
        for (int qq = 0; qq < 8; ++qq) acc[qq] += wv * bf2f((ushort_t)hv[qq]);
      }
    }
  }
#pragma unroll
  for (int q = 0; q < 8; ++q) {
    const float f = (bf2f((ushort_t)fv[q]) + acc[q] + gat_bias[lane * 8 + q]) * 0.5f;
    fv[q] = (short)f2bf(f);
  }
  *reinterpret_cast<bf16x8*>(&featb[o]) = fv;
}

// ---------- fused head: gather -> Wp -> 2x(2x(GEMM,tanh,LN), res LN) -> logit
__global__ __launch_bounds__(1024, 4) void head_fused(
    const ushort_t* __restrict__ featb, const int* __restrict__ tidx,
    const ushort_t* __restrict__ pWp, const float* __restrict__ bp,
    const ushort_t* __restrict__ pDW, const float* __restrict__ dnn_b,
    const float* __restrict__ dnn_g, const float* __restrict__ dnn_be,
    const float* __restrict__ res_g, const float* __restrict__ res_be,
    const float* __restrict__ Wc, const float* __restrict__ bc,
    float* __restrict__ out) {
  __shared__ __align__(16) ushort_t A_lds[16 * 512];
  __shared__ float lsum[16][16], lsq[16][16], meanv[16], rsv[16];
  const int tid = threadIdx.x;
  const int lane = tid & 63;
  const int wave = tid >> 6;      // 0..15
  const int nt0 = wave * 2;       // 2 n-tiles (32 cols) per wave
  const int c15 = lane & 15;
  const int rgrp = lane >> 4;

  {
    const int row = tid >> 6, col8 = tid & 63;
    const int g = tidx[blockIdx.x * 16 + row];
    const bf16x8 v = *reinterpret_cast<const bf16x8*>(&featb[(size_t)g * D + col8 * 8]);
    *reinterpret_cast<bf16x8*>(&A_lds[row * 512 + (col8 ^ (row & 7)) * 8]) = v;
  }
  __syncthreads();

  auto do_gemm = [&](const ushort_t* __restrict__ W, f32x4& a0, f32x4& a1) {
    a0 = f32x4{0.f, 0.f, 0.f, 0.f};
    a1 = f32x4{0.f, 0.f, 0.f, 0.f};
    bf16x8 c0 = *reinterpret_cast<const bf16x8*>(
        &W[(((size_t)nt0 * 16 + 0) << 9) + lane * 8]);
    bf16x8 c1 = *reinterpret_cast<const bf16x8*>(
        &W[(((size_t)(nt0 + 1) * 16 + 0) << 9) + lane * 8]);
#pragma unroll
    for (int kt = 0; kt < 16; ++kt) {
      bf16x8 n0 = c0, n1 = c1;
      if (kt < 15) {
        n0 = *reinterpret_cast<const bf16x8*>(
            &W[(((size_t)nt0 * 16 + kt + 1) << 9) + lane * 8]);
        n1 = *reinterpret_cast<const bf16x8*>(
            &W[(((size_t)(nt0 + 1) * 16 + kt + 1) << 9) + lane * 8]);
      }
      const int col8 = kt * 4 + rgrp;
      const bf16x8 af = *reinterpret_cast<const bf16x8*>(
          &A_lds[c15 * 512 + (col8 ^ (c15 & 7)) * 8]);
      a0 = __builtin_amdgcn_mfma_f32_16x16x32_bf16(af, c0, a0, 0, 0, 0);
      a1 = __builtin_amdgcn_mfma_f32_16x16x32_bf16(af, c1, a1, 0, 0, 0);
      c0 = n0;
      c1 = n1;
    }
  };

  auto block_ln = [&](f32x4& v0, f32x4& v1, const float* __restrict__ g,
                      const float* __restrict__ be) {
    float psum[4], psq[4];
#pragma unroll
    for (int r = 0; r < 4; ++r) {
      psum[r] = v0[r] + v1[r];
      psq[r] = v0[r] * v0[r] + v1[r] * v1[r];
    }
#pragma unroll
    for (int off = 8; off > 0; off >>= 1)
#pragma unroll
      for (int r = 0; r < 4; ++r) {
        psum[r] += __shfl_xor(psum[r], off);
        psq[r] += __shfl_xor(psq[r], off);
      }
    if (c15 == 0) {
#pragma unroll
      for (int r = 0; r < 4; ++r) {
        lsum[wave][rgrp * 4 + r] = psum[r];
        lsq[wave][rgrp * 4 + r] = psq[r];
      }
    }
    __syncthreads();
    if (tid < 16) {
      float s = 0.f, qq = 0.f;
#pragma unroll
      for (int w = 0; w < 16; ++w) { s += lsum[w][tid]; qq += lsq[w][tid]; }
      const float mean = s * (1.f / 512.f);
      const float var = qq * (1.f / 512.f) - mean * mean;
      meanv[tid] = mean;
      rsv[tid] = rsqrtf(var + 1e-5f);
    }
    __syncthreads();
    const int col0 = nt0 * 16 + c15;
    const int col1 = (nt0 + 1) * 16 + c15;
    const float g0 = g[col0], b0 = be[col0];
    const float g1 = g[col1], b1 = be[col1];
#pragma unroll
    for (int r = 0; r < 4; ++r) {
      const int row = rgrp * 4 + r;
      v0[r] = (v0[r] - meanv[row]) * rsv[row] * g0 + b0;
      v1[r] = (v1[r] - meanv[row]) * rsv[row] * g1 + b1;
    }
  };

  auto store_A = [&](const f32x4& v0, const f32x4& v1) {
    const int col0 = nt0 * 16 + c15;
    const int col1 = (nt0 + 1) * 16 + c15;
#pragma unroll
    for (int r = 0; r < 4; ++r) {
      const int row = rgrp * 4 + r;
      A_lds[row * 512 + (((col0 >> 3) ^ (row & 7)) << 3) + (col0 & 7)] = f2bf(v0[r]);
      A_lds[row * 512 + (((col1 >> 3) ^ (row & 7)) << 3) + (col1 & 7)] = f2bf(v1[r]);
    }
  };

  f32x4 sc0, sc1, acc0, acc1, ln0, ln1;

  do_gemm(pWp, acc0, acc1);
  {
    const float bv0 = bp[nt0 * 16 + c15];
    const float bv1 = bp[(nt0 + 1) * 16 + c15];
#pragma unroll
    for (int r = 0; r < 4; ++r) { sc0[r] = acc0[r] + bv0; sc1[r] = acc1[r] + bv1; }
  }
  __syncthreads();
  store_A(sc0, sc1);
  __syncthreads();

  for (int rb = 0; rb < 2; ++rb) {
    {
      const int st = rb * 2;
      do_gemm(pDW + (size_t)st * D * D, acc0, acc1);
      const float bv0 = dnn_b[st * D + nt0 * 16 + c15];
      const float bv1 = dnn_b[st * D + (nt0 + 1) * 16 + c15];
#pragma unroll
      for (int r = 0; r < 4; ++r) {
        acc0[r] = tanhf(acc0[r] + bv0);
        acc1[r] = tanhf(acc1[r] + bv1);
      }
      block_ln(acc0, acc1, dnn_g + st * D, dnn_be + st * D);
      store_A(acc0, acc1);
      __syncthreads();
    }
    {
      const int st = rb * 2 + 1;
      do_gemm(pDW + (size_t)st * D * D, ln0, ln1);
      const float bv0 = dnn_b[st * D + nt0 * 16 + c15];
      const float bv1 = dnn_b[st * D + (nt0 + 1) * 16 + c15];
#pragma unroll
      for (int r = 0; r < 4; ++r) {
        ln0[r] = tanhf(ln0[r] + bv0);
        ln1[r] = tanhf(ln1[r] + bv1);
      }
      block_ln(ln0, ln1, dnn_g + st * D, dnn_be + st * D);
    }
#pragma unroll
    for (int r = 0; r < 4; ++r) {
      acc0[r] = tanhf(sc0[r] + ln0[r]);
      acc1[r] = tanhf(sc1[r] + ln1[r]);
    }
    block_ln(acc0, acc1, res_g + rb * D, res_be + rb * D);
    sc0 = acc0;
    sc1 = acc1;
    if (rb == 0) {
      store_A(sc0, sc1);
      __syncthreads();
    }
  }

  float pr[4];
  {
    const float w0 = Wc[nt0 * 16 + c15];
    const float w1 = Wc[(nt0 + 1) * 16 + c15];
#pragma unroll
    for (int r = 0; r < 4; ++r) pr[r] = sc0[r] * w0 + sc1[r] * w1;
  }
#pragma unroll
  for (int off = 8; off > 0; off >>= 1)
#pragma unroll
    for (int r = 0; r < 4; ++r) pr[r] += __shfl_xor(pr[r], off);
  __syncthreads();
  if (c15 == 0) {
#pragma unroll
    for (int r = 0; r < 4; ++r) lsum[wave][rgrp * 4 + r] = pr[r];
  }
  __syncthreads();
  if (tid < 16) {
    float s = 0.f;
#pragma unroll
    for (int w = 0; w < 16; ++w) s += lsum[w][tid];
    out[blockIdx.x * 16 + tid] = 1.f / (1.f + expf(-(s + bc[0])));
  }
}

extern "C" void kernel_launch(void* const* d_in, const int* in_sizes, int n_in,
                              void* d_out, int out_size, void* d_ws, size_t ws_size,
                              hipStream_t stream) {
  (void)n_in; (void)out_size; (void)ws_size;
  const float* node_feat = (const float*)d_in[0];
  const int* edge0 = (const int*)d_in[1];
  const int* edge1 = (const int*)d_in[2];
  const int* tidx = (const int*)d_in[3];
  const float* Wt = (const float*)d_in[4];
  const float* bt = (const float*)d_in[5];
  const float* Wf = (const float*)d_in[6];
  const float* bfp = (const float*)d_in[7];
  const float* w_att = (const float*)d_in[8];
  const float* b_att = (const float*)d_in[9];
  const float* gat_bias = (const float*)d_in[10];
  const float* Wp = (const float*)d_in[11];
  const float* bp = (const float*)d_in[12];
  const float* dnn_W = (const float*)d_in[13];
  const float* dnn_b = (const float*)d_in[14];
  const float* dnn_g = (const float*)d_in[15];
  const float* dnn_be = (const float*)d_in[16];
  const float* res_g = (const float*)d_in[17];
  const float* res_be = (const float*)d_in[18];
  const float* Wc = (const float*)d_in[19];
  const float* bc = (const float*)d_in[20];
  float* out = (float*)d_out;

  const int Nn = in_sizes[0] / D;   // 30000
  const int E = in_sizes[1] / 2;    // 300000
  const int B = in_sizes[3];        // 4096
  const int K_IN = in_sizes[4] / D; // 512
  const int Mp = (Nn + 127) / 128 * 128;
  const int N2 = 2 * Nn;

  char* p = (char*)d_ws;
  auto alloc = [&](size_t bytes) -> char* {
    char* r = p;
    p += (bytes + 255) & ~(size_t)255;
    return r;
  };
  ushort_t* featb = (ushort_t*)alloc((size_t)Mp * D * 2);
  ushort_t* hb = (ushort_t*)alloc((size_t)Mp * D * 2);  // also nfb pre-hop
  float* sd = (float*)alloc((size_t)Nn * 4);
  float* ss = (float*)alloc((size_t)Nn * 4);
  float* sd_part = (float*)alloc((size_t)8 * Mp * 4);
  float* ss_part = (float*)alloc((size_t)8 * Mp * 4);
  int* cnt = (int*)alloc((size_t)N2 * 4);
  int* bucket = (int*)alloc((size_t)N2 * 64 * 4);
  int* tflag = (int*)alloc((size_t)Nn * 4);
  int* tlist = (int*)alloc((size_t)B * 4);
  int* tcount = (int*)alloc(256);
  ushort_t* pWt = (ushort_t*)alloc((size_t)K_IN * D * 2);
  ushort_t* pWf = (ushort_t*)alloc((size_t)D * D * 2);
  ushort_t* pWp = (ushort_t*)alloc((size_t)D * D * 2);
  ushort_t* pDWall = (ushort_t*)alloc((size_t)4 * D * D * 2);

  dim3 blk(256);
  const int nw4 = (Nn + 3) / 4;

  // ---- one-time packs / converts ----
  {
    pack_weight<<<(K_IN * D + 255) / 256, blk, 0, stream>>>(Wt, pWt, K_IN, D, 1);
    pack_weight<<<(D * D + 255) / 256, blk, 0, stream>>>(Wf, pWf, D, D, 1);
    pack_weight<<<(D * D + 255) / 256, blk, 0, stream>>>(Wp, pWp, D, D, 1);
    pack_weight<<<(4 * D * D + 255) / 256, blk, 0, stream>>>(dnn_W, pDWall, D, D, 4);
    conv_bf16_pad<<<((size_t)Mp * K_IN / 4 + 255) / 256, blk, 0, stream>>>(
        node_feat, hb /*nfb*/, Nn, Mp, K_IN);
  }

  // ---- bucket build + target set ----
  hipMemsetAsync(cnt, 0, (size_t)N2 * 4, stream);
  hipMemsetAsync(tflag, 0, (size_t)Nn * 4, stream);
  hipMemsetAsync(tcount, 0, 4, stream);
  fill_bucket<<<(E + 255) / 256, blk, 0, stream>>>(edge1, edge0, cnt, bucket, Nn, E);
  mark_targets<<<(B + 255) / 256, blk, 0, stream>>>(tidx, tflag, B);
  compact_targets<<<(Nn + 255) / 256, blk, 0, stream>>>(tflag, tlist, tcount, Nn);

  // ---- feat = node_feat @ Wt + bt ----
  gemm_mfma<<<dim3(4 * (Mp / 128)), dim3(512), 0, stream>>>(
      hb, pWt, bt, featb, nullptr, nullptr, nullptr, Mp, D, K_IN);

  // ---- two GAT hops (h-GEMM with fused band-partial attention dots) ----
  // hop1: all dst nodes (feat feeds hop0's GEMM). hop0: only target dsts
  // (featb rows are only read by the head gather afterwards).
  const int* hops[2] = {edge1, edge0};
  for (int hp = 0; hp < 2; ++hp) {
    gemm_mfma<<<dim3(4 * (Mp / 128)), dim3(512), 0, stream>>>(
        featb, pWf, bfp, hb, w_att, sd_part, ss_part, Mp, D, D);
    combine_dots<<<(Nn + 255) / 256, blk, 0, stream>>>(sd_part, ss_part, sd, ss, Mp, Nn);
    if (hp == 0) {
      gat_aggregate_w<<<nw4, blk, 0, stream>>>(
          featb, hb, sd, ss, hops[hp], hops[hp] + E, b_att, gat_bias,
          cnt + hp * Nn, bucket + (size_t)hp * Nn * 64, nullptr, nullptr, Nn, E);
    } else {
      gat_aggregate_w<<<(B + 3) / 4, blk, 0, stream>>>(
          featb, hb, sd, ss, hops[hp], hops[hp] + E, b_att, gat_bias,
          cnt + hp * Nn, bucket + (size_t)hp * Nn * 64, tlist, tcount, Nn, E);
    }
  }

  // ---- fused head ----
  head_fused<<<B / 16, dim3(1024), 0, stream>>>(
      featb, tidx, pWp, bp, pDWall, dnn_b, dnn_g, dnn_be, res_g, res_be,
      Wc, bc, out);
}

// Round 13
// 297.541 us; speedup vs baseline: 1.1525x; 1.0660x over previous
//
#include <hip/hip_runtime.h>

#define D 512
typedef unsigned short ushort_t;
typedef __attribute__((ext_vector_type(8))) short bf16x8;
typedef __attribute__((ext_vector_type(4))) float f32x4;

static __device__ __forceinline__ ushort_t f2bf(float f) {
  unsigned u = __float_as_uint(f);
  u += 0x7fffu + ((u >> 16) & 1u);  // RNE
  return (ushort_t)(u >> 16);
}
static __device__ __forceinline__ float bf2f(ushort_t h) {
  return __uint_as_float(((unsigned)h) << 16);
}

static __device__ __forceinline__ void gld_lds16(const void* g, void* lds) {
  __builtin_amdgcn_global_load_lds(
      (const __attribute__((address_space(1))) unsigned int*)g,
      (__attribute__((address_space(3))) unsigned int*)lds, 16, 0, 0);
}

// ---------- weight pack: 7 x W[512][512] fp32 -> fragment-ready bf16 --------
// mats: 0=Wt 1=Wf 2=Wp 3..6=dnn_W. Output contiguous at out + mat*per.
__global__ __launch_bounds__(256) void pack_weight7(
    const float* __restrict__ Wt, const float* __restrict__ Wf,
    const float* __restrict__ Wp, const float* __restrict__ Wd,
    ushort_t* __restrict__ out) {
  const int per = D * D;
  int i = blockIdx.x * 256 + threadIdx.x;
  if (i >= per * 7) return;
  const int mat = i / per;
  const int r = i - mat * per;
  const float* W;
  if (mat == 0) W = Wt;
  else if (mat == 1) W = Wf;
  else if (mat == 2) W = Wp;
  else W = Wd + (size_t)(mat - 3) * per;
  const int k = r / D, n = r - k * D;
  const int nt = n >> 4, col = n & 15, kt = k >> 5, kg = (k >> 3) & 3, j = k & 7;
  out[(size_t)mat * per + (((size_t)nt * (D >> 5) + kt) << 9) + ((kg << 4) + col) * 8 + j] =
      f2bf(W[r]);
}

// ---------- fp32 -> bf16 row-major with row padding ----------
__global__ __launch_bounds__(256) void conv_bf16_pad(
    const float* __restrict__ in, ushort_t* __restrict__ out, int M, int Mp, int K) {
  const size_t i4 = ((size_t)blockIdx.x * 256 + threadIdx.x) * 4;
  if (i4 >= (size_t)Mp * K) return;
  const int row = (int)(i4 / K);
  ushort4 o;
  if (row < M) {
    const float4 v = *reinterpret_cast<const float4*>(&in[i4]);
    o.x = f2bf(v.x); o.y = f2bf(v.y); o.z = f2bf(v.z); o.w = f2bf(v.w);
  } else {
    o.x = o.y = o.z = o.w = 0;
  }
  *reinterpret_cast<ushort4*>(&out[i4]) = o;
}

// ---------- init: zero cnt[N2], tflag[Nn], nflag[Nn], counters ----------
__global__ __launch_bounds__(256) void init_buffers(
    int* __restrict__ cnt, int* __restrict__ tflag, int* __restrict__ nflag,
    int* __restrict__ counters, int Nn, int N2) {
  const int i = blockIdx.x * 256 + threadIdx.x;
  if (i < N2) cnt[i] = 0;
  if (i < Nn) { tflag[i] = 0; nflag[i] = 0; }
  if (i < 2) counters[i * 64] = 0;
}

// ---------- bucket build (both hops) + mark targets ----------
__global__ void fill_bucket(const int* __restrict__ e1, const int* __restrict__ e0,
                            const int* __restrict__ tidx, int* __restrict__ tflag,
                            int* __restrict__ cnt, int* __restrict__ bucket,
                            int Nn, int E, int B) {
  const int e = blockIdx.x * blockDim.x + threadIdx.x;
  if (e < B) tflag[tidx[e]] = 1;
  if (e >= E) return;
  const int d1 = e1[e];
  const int p1 = atomicAdd(&cnt[d1], 1);
  if (p1 < 64) bucket[(size_t)d1 * 64 + p1] = e1[E + e];
  const int d0 = e0[e];
  const int p0 = atomicAdd(&cnt[Nn + d0], 1);
  if (p0 < 64) bucket[((size_t)(Nn + d0)) * 64 + p0] = e0[E + e];
}

// ---------- flag srcs of hop0 edges whose dst is a target ----------
__global__ void flag_srcs(const int* __restrict__ e0, const int* __restrict__ tflag,
                          int* __restrict__ nflag, int E) {
  const int e = blockIdx.x * blockDim.x + threadIdx.x;
  if (e < E && tflag[e0[e]]) nflag[e0[E + e]] = 1;
}

// ---------- compact both lists: tlist (targets), nlist (targets U srcs0) ----
__global__ void compact2(const int* __restrict__ tflag, const int* __restrict__ nflag,
                         int* __restrict__ tlist, int* __restrict__ nlist,
                         int* __restrict__ counters, int Nn) {
  const int i = blockIdx.x * 256 + threadIdx.x;
  if (i >= Nn) return;
  const int tf = tflag[i];
  if (tf) tlist[atomicAdd(&counters[0], 1)] = i;
  if (tf | nflag[i]) nlist[atomicAdd(&counters[64], 1)] = i;
}

// ---------- node MFMA GEMM: 128x128 tile, 8 waves (4x2), 2-phase dbuf -------
// optional fused attention dots: per-64-col-band partials, atomic-free.
__global__ __launch_bounds__(512) void gemm_mfma(
    const ushort_t* __restrict__ A, const ushort_t* __restrict__ Bp,
    const float* __restrict__ bias, ushort_t* __restrict__ C16,
    const float* __restrict__ watt, float* __restrict__ sd_part,
    float* __restrict__ ss_part, int Mp, int N, int K) {
  __shared__ __align__(16) ushort_t As[2][8 * 512];
  __shared__ __align__(16) ushort_t Bs[2][8 * 512];
  const int nwg = gridDim.x;
  const int q = nwg >> 3, rm = nwg & 7;
  const int xcd = blockIdx.x & 7, kk = blockIdx.x >> 3;
  const int lin = (xcd < rm ? xcd * (q + 1) : rm * (q + 1) + (xcd - rm) * q) + kk;
  const int m0 = (lin >> 2) * 128;
  const int n0 = (lin & 3) * 128;
  const int tid = threadIdx.x;
  const int lane = tid & 63;
  const int wid = tid >> 6;        // 0..7
  const int wm = wid >> 1;         // 0..3 (32-row band)
  const int wn = wid & 1;          // 0..1 (64-col band)
  const int arow = lane & 15;
  const int akoff = (lane >> 4) * 8;
  const int c15 = lane & 15;
  const int rgrp = lane >> 4;
  const int kt32 = K >> 5;
  f32x4 acc[2][4] = {};

  auto stage = [&](int kt, int b) {  // 2 gld per wave
    const int k0 = kt * 32;
    gld_lds16(&A[(size_t)(m0 + wid * 16 + arow) * K + k0 + akoff],
              &As[b][wid * 512]);
    gld_lds16(&Bp[(((size_t)(n0 / 16 + wid) * kt32 + kt) << 9) + lane * 8],
              &Bs[b][wid * 512]);
  };

  stage(0, 0);
  __syncthreads();
  int cur = 0;
  for (int t = 0; t < kt32; ++t) {
    if (t + 1 < kt32) stage(t + 1, cur ^ 1);
    bf16x8 af[2], bfr[4];
#pragma unroll
    for (int mi = 0; mi < 2; ++mi)
      af[mi] = *reinterpret_cast<const bf16x8*>(&As[cur][(wm * 2 + mi) * 512 + lane * 8]);
#pragma unroll
    for (int ni = 0; ni < 4; ++ni)
      bfr[ni] = *reinterpret_cast<const bf16x8*>(&Bs[cur][(wn * 4 + ni) * 512 + lane * 8]);
#pragma unroll
    for (int mi = 0; mi < 2; ++mi)
#pragma unroll
      for (int ni = 0; ni < 4; ++ni)
        acc[mi][ni] = __builtin_amdgcn_mfma_f32_16x16x32_bf16(af[mi], bfr[ni], acc[mi][ni], 0, 0, 0);
    __syncthreads();
    cur ^= 1;
  }
  const int band = (n0 >> 6) + wn;  // 0..7 (64-col bands)
#pragma unroll
  for (int mi = 0; mi < 2; ++mi) {
    const int row = m0 + wm * 32 + mi * 16 + (rgrp << 2);
#pragma unroll
    for (int r = 0; r < 4; ++r) {
      float psd = 0.f, pss = 0.f;
#pragma unroll
      for (int ni = 0; ni < 4; ++ni) {
        const int col = n0 + wn * 64 + ni * 16 + c15;
        const float v = acc[mi][ni][r] + bias[col];
        C16[(size_t)(row + r) * N + col] = f2bf(v);
        if (watt) {
          psd += v * watt[col];
          pss += v * watt[D + col];
        }
      }
      if (watt) {
#pragma unroll
        for (int off = 8; off > 0; off >>= 1) {
          psd += __shfl_xor(psd, off);
          pss += __shfl_xor(pss, off);
        }
        if (c15 == 0) {
          sd_part[(size_t)band * Mp + row + r] = psd;
          ss_part[(size_t)band * Mp + row + r] = pss;
        }
      }
    }
  }
}

// ---------- combine per-band dot partials ----------
__global__ __launch_bounds__(256) void combine_dots(
    const float* __restrict__ sd_part, const float* __restrict__ ss_part,
    float* __restrict__ sd, float* __restrict__ ss, int Mp, int Nn) {
  const int i = blockIdx.x * 256 + threadIdx.x;
  if (i >= Nn) return;
  float a = 0.f, b = 0.f;
#pragma unroll
  for (int bnd = 0; bnd < 8; ++bnd) {
    a += sd_part[(size_t)bnd * Mp + i];
    b += ss_part[(size_t)bnd * Mp + i];
  }
  sd[i] = a;
  ss[i] = b;
}

// ---------- GAT softmax + aggregate: 1 wave/dst, bf16x8, 4x unroll ----------
// dstlist + device count: process only listed dst nodes.
__global__ __launch_bounds__(256) void gat_aggregate_w(
    ushort_t* __restrict__ featb, const ushort_t* __restrict__ hb,
    const float* __restrict__ sd, const float* __restrict__ ss,
    const int* __restrict__ di, const int* __restrict__ si,
    const float* __restrict__ b_att_p, const float* __restrict__ gat_bias,
    const int* __restrict__ cnt, const int* __restrict__ bucket,
    const int* __restrict__ dstlist, const int* __restrict__ dcount,
    int Nn, int E) {
  const int gidx = blockIdx.x * 4 + (threadIdx.x >> 6);
  const int lane = threadIdx.x & 63;
  if (gidx >= *dcount) return;
  const int dst = dstlist[gidx];
  const int deg = cnt[dst];
  const float sdd = sd[dst];
  const float ba = b_att_p[0];
  const size_t o = (size_t)dst * D + lane * 8;
  bf16x8 fv = *reinterpret_cast<const bf16x8*>(&featb[o]);  // hoisted RMW load
  float acc[8] = {};
  if (deg <= 64) {
    const bool valid = lane < deg;
    const int slane = valid ? bucket[(size_t)dst * 64 + lane] : 0;
    const float e = valid ? tanhf(sdd + ss[slane] + ba) : -1e30f;
    float m = e;
#pragma unroll
    for (int off = 32; off > 0; off >>= 1) m = fmaxf(m, __shfl_xor(m, off));
    const float a = valid ? expf(e - m) : 0.f;
    float s = a;
#pragma unroll
    for (int off = 32; off > 0; off >>= 1) s += __shfl_xor(s, off);
    const float w = a * ((s > 0.f) ? 1.f / s : 0.f);  // per-lane alpha
    int k = 0;
    for (; k + 3 < deg; k += 4) {
      const float w0 = __shfl(w, k), w1 = __shfl(w, k + 1);
      const float w2 = __shfl(w, k + 2), w3 = __shfl(w, k + 3);
      const int s0 = __shfl(slane, k), s1 = __shfl(slane, k + 1);
      const int s2 = __shfl(slane, k + 2), s3 = __shfl(slane, k + 3);
      const bf16x8 h0 = *reinterpret_cast<const bf16x8*>(&hb[(size_t)s0 * D + lane * 8]);
      const bf16x8 h1 = *reinterpret_cast<const bf16x8*>(&hb[(size_t)s1 * D + lane * 8]);
      const bf16x8 h2 = *reinterpret_cast<const bf16x8*>(&hb[(size_t)s2 * D + lane * 8]);
      const bf16x8 h3 = *reinterpret_cast<const bf16x8*>(&hb[(size_t)s3 * D + lane * 8]);
#pragma unroll
      for (int qq = 0; qq < 8; ++qq) {
        const float t0 = w0 * bf2f((ushort_t)h0[qq]) + w1 * bf2f((ushort_t)h1[qq]);
        const float t1 = w2 * bf2f((ushort_t)h2[qq]) + w3 * bf2f((ushort_t)h3[qq]);
        acc[qq] += t0 + t1;
      }
    }
    for (; k < deg; ++k) {
      const float wk = __shfl(w, k);
      const int sk = __shfl(slane, k);
      const bf16x8 h0 = *reinterpret_cast<const bf16x8*>(&hb[(size_t)sk * D + lane * 8]);
#pragma unroll
      for (int qq = 0; qq < 8; ++qq) acc[qq] += wk * bf2f((ushort_t)h0[qq]);
    }
  } else {
    // overflow fallback (deg > 64): ballot-scan the raw edge list. Correct for
    // any degree; effectively never taken for this graph.
    float m = -1e30f;
    for (int e = lane; e < E; e += 64)
      if (di[e] == dst) m = fmaxf(m, tanhf(sdd + ss[si[e]] + ba));
#pragma unroll
    for (int off = 32; off > 0; off >>= 1) m = fmaxf(m, __shfl_xor(m, off));
    float s = 0.f;
    for (int e = lane; e < E; e += 64)
      if (di[e] == dst) s += expf(tanhf(sdd + ss[si[e]] + ba) - m);
#pragma unroll
    for (int off = 32; off > 0; off >>= 1) s += __shfl_xor(s, off);
    const float inv = (s > 0.f) ? 1.f / s : 0.f;
    for (int base = 0; base < E; base += 64) {
      const int e = base + lane;
      const bool hit = (e < E) && (di[e] == dst);
      unsigned long long mask = __ballot(hit);
      const int sidx = hit ? si[e] : 0;
      const float aval = hit ? expf(tanhf(sdd + ss[sidx] + ba) - m) * inv : 0.f;
      while (mask) {
        const int l = __ffsll((long long)mask) - 1;
        mask &= mask - 1;
        const float wv = __shfl(aval, l);
        const int sk = __shfl(sidx, l);
        const bf16x8 hv = *reinterpret_cast<const bf16x8*>(&hb[(size_t)sk * D + lane * 8]);
#pragma unroll
        for (int qq = 0; qq < 8; ++qq) acc[qq] += wv * bf2f((ushort_t)hv[qq]);
      }
    }
  }
#pragma unroll
  for (int q = 0; q < 8; ++q) {
    const float f = (bf2f((ushort_t)fv[q]) + acc[q] + gat_bias[lane * 8 + q]) * 0.5f;
    fv[q] = (short)f2bf(f);
  }
  *reinterpret_cast<bf16x8*>(&featb[o]) = fv;
}

// ---------- fused head: gather -> Wp -> 2x(2x(GEMM,tanh,LN), res LN) -> logit
__global__ __launch_bounds__(1024, 4) void head_fused(
    const ushort_t* __restrict__ featb, const int* __restrict__ tidx,
    const ushort_t* __restrict__ pWp, const float* __restrict__ bp,
    const ushort_t* __restrict__ pDW, const float* __restrict__ dnn_b,
    const float* __restrict__ dnn_g, const float* __restrict__ dnn_be,
    const float* __restrict__ res_g, const float* __restrict__ res_be,
    const float* __restrict__ Wc, const float* __restrict__ bc,
    float* __restrict__ out) {
  __shared__ __align__(16) ushort_t A_lds[16 * 512];
  __shared__ float lsum[16][16], lsq[16][16], meanv[16], rsv[16];
  const int tid = threadIdx.x;
  const int lane = tid & 63;
  const int wave = tid >> 6;      // 0..15
  const int nt0 = wave * 2;       // 2 n-tiles (32 cols) per wave
  const int c15 = lane & 15;
  const int rgrp = lane >> 4;

  {
    const int row = tid >> 6, col8 = tid & 63;
    const int g = tidx[blockIdx.x * 16 + row];
    const bf16x8 v = *reinterpret_cast<const bf16x8*>(&featb[(size_t)g * D + col8 * 8]);
    *reinterpret_cast<bf16x8*>(&A_lds[row * 512 + (col8 ^ (row & 7)) * 8]) = v;
  }
  __syncthreads();

  auto do_gemm = [&](const ushort_t* __restrict__ W, f32x4& a0, f32x4& a1) {
    a0 = f32x4{0.f, 0.f, 0.f, 0.f};
    a1 = f32x4{0.f, 0.f, 0.f, 0.f};
    bf16x8 c0 = *reinterpret_cast<const bf16x8*>(
        &W[(((size_t)nt0 * 16 + 0) << 9) + lane * 8]);
    bf16x8 c1 = *reinterpret_cast<const bf16x8*>(
        &W[(((size_t)(nt0 + 1) * 16 + 0) << 9) + lane * 8]);
#pragma unroll
    for (int kt = 0; kt < 16; ++kt) {
      bf16x8 n0 = c0, n1 = c1;
      if (kt < 15) {
        n0 = *reinterpret_cast<const bf16x8*>(
            &W[(((size_t)nt0 * 16 + kt + 1) << 9) + lane * 8]);
        n1 = *reinterpret_cast<const bf16x8*>(
            &W[(((size_t)(nt0 + 1) * 16 + kt + 1) << 9) + lane * 8]);
      }
      const int col8 = kt * 4 + rgrp;
      const bf16x8 af = *reinterpret_cast<const bf16x8*>(
          &A_lds[c15 * 512 + (col8 ^ (c15 & 7)) * 8]);
      a0 = __builtin_amdgcn_mfma_f32_16x16x32_bf16(af, c0, a0, 0, 0, 0);
      a1 = __builtin_amdgcn_mfma_f32_16x16x32_bf16(af, c1, a1, 0, 0, 0);
      c0 = n0;
      c1 = n1;
    }
  };

  auto block_ln = [&](f32x4& v0, f32x4& v1, const float* __restrict__ g,
                      const float* __restrict__ be) {
    float psum[4], psq[4];
#pragma unroll
    for (int r = 0; r < 4; ++r) {
      psum[r] = v0[r] + v1[r];
      psq[r] = v0[r] * v0[r] + v1[r] * v1[r];
    }
#pragma unroll
    for (int off = 8; off > 0; off >>= 1)
#pragma unroll
      for (int r = 0; r < 4; ++r) {
        psum[r] += __shfl_xor(psum[r], off);
        psq[r] += __shfl_xor(psq[r], off);
      }
    if (c15 == 0) {
#pragma unroll
      for (int r = 0; r < 4; ++r) {
        lsum[wave][rgrp * 4 + r] = psum[r];
        lsq[wave][rgrp * 4 + r] = psq[r];
      }
    }
    __syncthreads();
    if (tid < 16) {
      float s = 0.f, qq = 0.f;
#pragma unroll
      for (int w = 0; w < 16; ++w) { s += lsum[w][tid]; qq += lsq[w][tid]; }
      const float mean = s * (1.f / 512.f);
      const float var = qq * (1.f / 512.f) - mean * mean;
      meanv[tid] = mean;
      rsv[tid] = rsqrtf(var + 1e-5f);
    }
    __syncthreads();
    const int col0 = nt0 * 16 + c15;
    const int col1 = (nt0 + 1) * 16 + c15;
    const float g0 = g[col0], b0 = be[col0];
    const float g1 = g[col1], b1 = be[col1];
#pragma unroll
    for (int r = 0; r < 4; ++r) {
      const int row = rgrp * 4 + r;
      v0[r] = (v0[r] - meanv[row]) * rsv[row] * g0 + b0;
      v1[r] = (v1[r] - meanv[row]) * rsv[row] * g1 + b1;
    }
  };

  auto store_A = [&](const f32x4& v0, const f32x4& v1) {
    const int col0 = nt0 * 16 + c15;
    const int col1 = (nt0 + 1) * 16 + c15;
#pragma unroll
    for (int r = 0; r < 4; ++r) {
      const int row = rgrp * 4 + r;
      A_lds[row * 512 + (((col0 >> 3) ^ (row & 7)) << 3) + (col0 & 7)] = f2bf(v0[r]);
      A_lds[row * 512 + (((col1 >> 3) ^ (row & 7)) << 3) + (col1 & 7)] = f2bf(v1[r]);
    }
  };

  f32x4 sc0, sc1, acc0, acc1, ln0, ln1;

  do_gemm(pWp, acc0, acc1);
  {
    const float bv0 = bp[nt0 * 16 + c15];
    const float bv1 = bp[(nt0 + 1) * 16 + c15];
#pragma unroll
    for (int r = 0; r < 4; ++r) { sc0[r] = acc0[r] + bv0; sc1[r] = acc1[r] + bv1; }
  }
  __syncthreads();
  store_A(sc0, sc1);
  __syncthreads();

  for (int rb = 0; rb < 2; ++rb) {
    {
      const int st = rb * 2;
      do_gemm(pDW + (size_t)st * D * D, acc0, acc1);
      const float bv0 = dnn_b[st * D + nt0 * 16 + c15];
      const float bv1 = dnn_b[st * D + (nt0 + 1) * 16 + c15];
#pragma unroll
      for (int r = 0; r < 4; ++r) {
        acc0[r] = tanhf(acc0[r] + bv0);
        acc1[r] = tanhf(acc1[r] + bv1);
      }
      block_ln(acc0, acc1, dnn_g + st * D, dnn_be + st * D);
      store_A(acc0, acc1);
      __syncthreads();
    }
    {
      const int st = rb * 2 + 1;
      do_gemm(pDW + (size_t)st * D * D, ln0, ln1);
      const float bv0 = dnn_b[st * D + nt0 * 16 + c15];
      const float bv1 = dnn_b[st * D + (nt0 + 1) * 16 + c15];
#pragma unroll
      for (int r = 0; r < 4; ++r) {
        ln0[r] = tanhf(ln0[r] + bv0);
        ln1[r] = tanhf(ln1[r] + bv1);
      }
      block_ln(ln0, ln1, dnn_g + st * D, dnn_be + st * D);
    }
#pragma unroll
    for (int r = 0; r < 4; ++r) {
      acc0[r] = tanhf(sc0[r] + ln0[r]);
      acc1[r] = tanhf(sc1[r] + ln1[r]);
    }
    block_ln(acc0, acc1, res_g + rb * D, res_be + rb * D);
    sc0 = acc0;
    sc1 = acc1;
    if (rb == 0) {
      store_A(sc0, sc1);
      __syncthreads();
    }
  }

  float pr[4];
  {
    const float w0 = Wc[nt0 * 16 + c15];
    const float w1 = Wc[(nt0 + 1) * 16 + c15];
#pragma unroll
    for (int r = 0; r < 4; ++r) pr[r] = sc0[r] * w0 + sc1[r] * w1;
  }
#pragma unroll
  for (int off = 8; off > 0; off >>= 1)
#pragma unroll
    for (int r = 0; r < 4; ++r) pr[r] += __shfl_xor(pr[r], off);
  __syncthreads();
  if (c15 == 0) {
#pragma unroll
    for (int r = 0; r < 4; ++r) lsum[wave][rgrp * 4 + r] = pr[r];
  }
  __syncthreads();
  if (tid < 16) {
    float s = 0.f;
#pragma unroll
    for (int w = 0; w < 16; ++w) s += lsum[w][tid];
    out[blockIdx.x * 16 + tid] = 1.f / (1.f + expf(-(s + bc[0])));
  }
}

extern "C" void kernel_launch(void* const* d_in, const int* in_sizes, int n_in,
                              void* d_out, int out_size, void* d_ws, size_t ws_size,
                              hipStream_t stream) {
  (void)n_in; (void)out_size; (void)ws_size;
  const float* node_feat = (const float*)d_in[0];
  const int* edge0 = (const int*)d_in[1];
  const int* edge1 = (const int*)d_in[2];
  const int* tidx = (const int*)d_in[3];
  const float* Wt = (const float*)d_in[4];
  const float* bt = (const float*)d_in[5];
  const float* Wf = (const float*)d_in[6];
  const float* bfp = (const float*)d_in[7];
  const float* w_att = (const float*)d_in[8];
  const float* b_att = (const float*)d_in[9];
  const float* gat_bias = (const float*)d_in[10];
  const float* Wp = (const float*)d_in[11];
  const float* bp = (const float*)d_in[12];
  const float* dnn_W = (const float*)d_in[13];
  const float* dnn_b = (const float*)d_in[14];
  const float* dnn_g = (const float*)d_in[15];
  const float* dnn_be = (const float*)d_in[16];
  const float* res_g = (const float*)d_in[17];
  const float* res_be = (const float*)d_in[18];
  const float* Wc = (const float*)d_in[19];
  const float* bc = (const float*)d_in[20];
  float* out = (float*)d_out;

  const int Nn = in_sizes[0] / D;   // 30000
  const int E = in_sizes[1] / 2;    // 300000
  const int B = in_sizes[3];        // 4096
  const int K_IN = in_sizes[4] / D; // 512 (== D for this model)
  const int Mp = (Nn + 127) / 128 * 128;
  const int N2 = 2 * Nn;

  char* p = (char*)d_ws;
  auto alloc = [&](size_t bytes) -> char* {
    char* r = p;
    p += (bytes + 255) & ~(size_t)255;
    return r;
  };
  ushort_t* featb = (ushort_t*)alloc((size_t)Mp * D * 2);
  ushort_t* hb = (ushort_t*)alloc((size_t)Mp * D * 2);  // also nfb pre-hop
  float* sd = (float*)alloc((size_t)Nn * 4);
  float* ss = (float*)alloc((size_t)Nn * 4);
  float* sd_part = (float*)alloc((size_t)8 * Mp * 4);
  float* ss_part = (float*)alloc((size_t)8 * Mp * 4);
  int* cnt = (int*)alloc((size_t)N2 * 4);
  int* bucket = (int*)alloc((size_t)N2 * 64 * 4);
  int* tflag = (int*)alloc((size_t)Nn * 4);
  int* nflag = (int*)alloc((size_t)Nn * 4);
  int* tlist = (int*)alloc((size_t)B * 4);
  int* nlist = (int*)alloc((size_t)Nn * 4);
  int* counters = (int*)alloc(512);  // [0]=tcount, [64]=ncount
  ushort_t* pAll = (ushort_t*)alloc((size_t)7 * D * D * 2);
  ushort_t* pWt = pAll;
  ushort_t* pWf = pAll + (size_t)D * D;
  ushort_t* pWp = pAll + (size_t)2 * D * D;
  ushort_t* pDWall = pAll + (size_t)3 * D * D;

  dim3 blk(256);

  // ---- one-time packs / converts (K_IN == D for this model) ----
  pack_weight7<<<(7 * D * D + 255) / 256, blk, 0, stream>>>(Wt, Wf, Wp, dnn_W, pAll);
  conv_bf16_pad<<<((size_t)Mp * K_IN / 4 + 255) / 256, blk, 0, stream>>>(
      node_feat, hb /*nfb*/, Nn, Mp, K_IN);

  // ---- init + bucket build + target/N0 sets ----
  init_buffers<<<(N2 + 255) / 256, blk, 0, stream>>>(cnt, tflag, nflag, counters, Nn, N2);
  fill_bucket<<<(E + 255) / 256, blk, 0, stream>>>(edge1, edge0, tidx, tflag,
                                                   cnt, bucket, Nn, E, B);
  flag_srcs<<<(E + 255) / 256, blk, 0, stream>>>(edge0, tflag, nflag, E);
  compact2<<<(Nn + 255) / 256, blk, 0, stream>>>(tflag, nflag, tlist, nlist,
                                                 counters, Nn);

  // ---- feat = node_feat @ Wt + bt ----
  gemm_mfma<<<dim3(4 * (Mp / 128)), dim3(512), 0, stream>>>(
      hb, pWt, bt, featb, nullptr, nullptr, nullptr, Mp, D, K_IN);

  // ---- two GAT hops (h-GEMM with fused band-partial attention dots) ----
  // hop1: only dsts in N0 = targets U srcs(hop0 edges -> targets); other feat
  // rows flow into h rows that are never read. hop0: only target dsts.
  const int* hops[2] = {edge1, edge0};
  for (int hp = 0; hp < 2; ++hp) {
    gemm_mfma<<<dim3(4 * (Mp / 128)), dim3(512), 0, stream>>>(
        featb, pWf, bfp, hb, w_att, sd_part, ss_part, Mp, D, D);
    combine_dots<<<(Nn + 255) / 256, blk, 0, stream>>>(sd_part, ss_part, sd, ss, Mp, Nn);
    if (hp == 0) {
      gat_aggregate_w<<<(Nn + 3) / 4, blk, 0, stream>>>(
          featb, hb, sd, ss, hops[hp], hops[hp] + E, b_att, gat_bias,
          cnt + hp * Nn, bucket + (size_t)hp * Nn * 64, nlist, &counters[64], Nn, E);
    } else {
      gat_aggregate_w<<<(B + 3) / 4, blk, 0, stream>>>(
          featb, hb, sd, ss, hops[hp], hops[hp] + E, b_att, gat_bias,
          cnt + hp * Nn, bucket + (size_t)hp * Nn * 64, tlist, &counters[0], Nn, E);
    }
  }

  // ---- fused head ----
  head_fused<<<B / 16, dim3(1024), 0, stream>>>(
      featb, tidx, pWp, bp, pDWall, dnn_b, dnn_g, dnn_be, res_g, res_be,
      Wc, bc, out);
}

// Round 14
// 288.962 us; speedup vs baseline: 1.1867x; 1.0297x over previous
//
#include <hip/hip_runtime.h>

#define D 512
typedef unsigned short ushort_t;
typedef __attribute__((ext_vector_type(8))) short bf16x8;
typedef __attribute__((ext_vector_type(4))) float f32x4;

static __device__ __forceinline__ ushort_t f2bf(float f) {
  unsigned u = __float_as_uint(f);
  u += 0x7fffu + ((u >> 16) & 1u);  // RNE
  return (ushort_t)(u >> 16);
}
static __device__ __forceinline__ float bf2f(ushort_t h) {
  return __uint_as_float(((unsigned)h) << 16);
}

static __device__ __forceinline__ void gld_lds16(const void* g, void* lds) {
  __builtin_amdgcn_global_load_lds(
      (const __attribute__((address_space(1))) unsigned int*)g,
      (__attribute__((address_space(3))) unsigned int*)lds, 16, 0, 0);
}

// ---------- weight pack: 7 x W[512][512] fp32 -> fragment-ready bf16 --------
__global__ __launch_bounds__(256) void pack_weight7(
    const float* __restrict__ Wt, const float* __restrict__ Wf,
    const float* __restrict__ Wp, const float* __restrict__ Wd,
    ushort_t* __restrict__ out) {
  const int per = D * D;
  int i = blockIdx.x * 256 + threadIdx.x;
  if (i >= per * 7) return;
  const int mat = i / per;
  const int r = i - mat * per;
  const float* W;
  if (mat == 0) W = Wt;
  else if (mat == 1) W = Wf;
  else if (mat == 2) W = Wp;
  else W = Wd + (size_t)(mat - 3) * per;
  const int k = r / D, n = r - k * D;
  const int nt = n >> 4, col = n & 15, kt = k >> 5, kg = (k >> 3) & 3, j = k & 7;
  out[(size_t)mat * per + (((size_t)nt * (D >> 5) + kt) << 9) + ((kg << 4) + col) * 8 + j] =
      f2bf(W[r]);
}

// ---------- fp32 -> bf16 row-major with row padding ----------
__global__ __launch_bounds__(256) void conv_bf16_pad(
    const float* __restrict__ in, ushort_t* __restrict__ out, int M, int Mp, int K) {
  const size_t i4 = ((size_t)blockIdx.x * 256 + threadIdx.x) * 4;
  if (i4 >= (size_t)Mp * K) return;
  const int row = (int)(i4 / K);
  ushort4 o;
  if (row < M) {
    const float4 v = *reinterpret_cast<const float4*>(&in[i4]);
    o.x = f2bf(v.x); o.y = f2bf(v.y); o.z = f2bf(v.z); o.w = f2bf(v.w);
  } else {
    o.x = o.y = o.z = o.w = 0;
  }
  *reinterpret_cast<ushort4*>(&out[i4]) = o;
}

// ---------- init: zero cnt[N2], tflag[Nn], nflag[Nn], counters ----------
__global__ __launch_bounds__(256) void init_buffers(
    int* __restrict__ cnt, int* __restrict__ tflag, int* __restrict__ nflag,
    int* __restrict__ counters, int Nn, int N2) {
  const int i = blockIdx.x * 256 + threadIdx.x;
  if (i < N2) cnt[i] = 0;
  if (i < Nn) { tflag[i] = 0; nflag[i] = 0; }
  if (i < 2) counters[i * 64] = 0;
}

// ---------- bucket build (both hops) + mark targets ----------
__global__ void fill_bucket(const int* __restrict__ e1, const int* __restrict__ e0,
                            const int* __restrict__ tidx, int* __restrict__ tflag,
                            int* __restrict__ cnt, int* __restrict__ bucket,
                            int Nn, int E, int B) {
  const int e = blockIdx.x * blockDim.x + threadIdx.x;
  if (e < B) tflag[tidx[e]] = 1;
  if (e >= E) return;
  const int d1 = e1[e];
  const int p1 = atomicAdd(&cnt[d1], 1);
  if (p1 < 64) bucket[(size_t)d1 * 64 + p1] = e1[E + e];
  const int d0 = e0[e];
  const int p0 = atomicAdd(&cnt[Nn + d0], 1);
  if (p0 < 64) bucket[((size_t)(Nn + d0)) * 64 + p0] = e0[E + e];
}

// ---------- flag srcs of hop0 edges whose dst is a target ----------
__global__ void flag_srcs(const int* __restrict__ e0, const int* __restrict__ tflag,
                          int* __restrict__ nflag, int E) {
  const int e = blockIdx.x * blockDim.x + threadIdx.x;
  if (e < E && tflag[e0[e]]) nflag[e0[E + e]] = 1;
}

// ---------- compact both lists: tlist (targets), nlist (targets U srcs0) ----
__global__ void compact2(const int* __restrict__ tflag, const int* __restrict__ nflag,
                         int* __restrict__ tlist, int* __restrict__ nlist,
                         int* __restrict__ counters, int Nn) {
  const int i = blockIdx.x * 256 + threadIdx.x;
  if (i >= Nn) return;
  const int tf = tflag[i];
  if (tf) tlist[atomicAdd(&counters[0], 1)] = i;
  if (tf | nflag[i]) nlist[atomicAdd(&counters[64], 1)] = i;
}

// ---------- node MFMA GEMM: 128x128 tile, 8 waves (4x2), 2-phase dbuf -------
__global__ __launch_bounds__(512) void gemm_mfma(
    const ushort_t* __restrict__ A, const ushort_t* __restrict__ Bp,
    const float* __restrict__ bias, ushort_t* __restrict__ C16,
    const float* __restrict__ watt, float* __restrict__ sd_part,
    float* __restrict__ ss_part, int Mp, int N, int K) {
  __shared__ __align__(16) ushort_t As[2][8 * 512];
  __shared__ __align__(16) ushort_t Bs[2][8 * 512];
  const int nwg = gridDim.x;
  const int q = nwg >> 3, rm = nwg & 7;
  const int xcd = blockIdx.x & 7, kk = blockIdx.x >> 3;
  const int lin = (xcd < rm ? xcd * (q + 1) : rm * (q + 1) + (xcd - rm) * q) + kk;
  const int m0 = (lin >> 2) * 128;
  const int n0 = (lin & 3) * 128;
  const int tid = threadIdx.x;
  const int lane = tid & 63;
  const int wid = tid >> 6;        // 0..7
  const int wm = wid >> 1;         // 0..3 (32-row band)
  const int wn = wid & 1;          // 0..1 (64-col band)
  const int arow = lane & 15;
  const int akoff = (lane >> 4) * 8;
  const int c15 = lane & 15;
  const int rgrp = lane >> 4;
  const int kt32 = K >> 5;
  f32x4 acc[2][4] = {};

  auto stage = [&](int kt, int b) {  // 2 gld per wave
    const int k0 = kt * 32;
    gld_lds16(&A[(size_t)(m0 + wid * 16 + arow) * K + k0 + akoff],
              &As[b][wid * 512]);
    gld_lds16(&Bp[(((size_t)(n0 / 16 + wid) * kt32 + kt) << 9) + lane * 8],
              &Bs[b][wid * 512]);
  };

  stage(0, 0);
  __syncthreads();
  int cur = 0;
  for (int t = 0; t < kt32; ++t) {
    if (t + 1 < kt32) stage(t + 1, cur ^ 1);
    bf16x8 af[2], bfr[4];
#pragma unroll
    for (int mi = 0; mi < 2; ++mi)
      af[mi] = *reinterpret_cast<const bf16x8*>(&As[cur][(wm * 2 + mi) * 512 + lane * 8]);
#pragma unroll
    for (int ni = 0; ni < 4; ++ni)
      bfr[ni] = *reinterpret_cast<const bf16x8*>(&Bs[cur][(wn * 4 + ni) * 512 + lane * 8]);
#pragma unroll
    for (int mi = 0; mi < 2; ++mi)
#pragma unroll
      for (int ni = 0; ni < 4; ++ni)
        acc[mi][ni] = __builtin_amdgcn_mfma_f32_16x16x32_bf16(af[mi], bfr[ni], acc[mi][ni], 0, 0, 0);
    __syncthreads();
    cur ^= 1;
  }
  const int band = (n0 >> 6) + wn;  // 0..7 (64-col bands)
#pragma unroll
  for (int mi = 0; mi < 2; ++mi) {
    const int row = m0 + wm * 32 + mi * 16 + (rgrp << 2);
#pragma unroll
    for (int r = 0; r < 4; ++r) {
      float psd = 0.f, pss = 0.f;
#pragma unroll
      for (int ni = 0; ni < 4; ++ni) {
        const int col = n0 + wn * 64 + ni * 16 + c15;
        const float v = acc[mi][ni][r] + bias[col];
        C16[(size_t)(row + r) * N + col] = f2bf(v);
        if (watt) {
          psd += v * watt[col];
          pss += v * watt[D + col];
        }
      }
      if (watt) {
#pragma unroll
        for (int off = 8; off > 0; off >>= 1) {
          psd += __shfl_xor(psd, off);
          pss += __shfl_xor(pss, off);
        }
        if (c15 == 0) {
          sd_part[(size_t)band * Mp + row + r] = psd;
          ss_part[(size_t)band * Mp + row + r] = pss;
        }
      }
    }
  }
}

// ---------- combine per-band dot partials ----------
__global__ __launch_bounds__(256) void combine_dots(
    const float* __restrict__ sd_part, const float* __restrict__ ss_part,
    float* __restrict__ sd, float* __restrict__ ss, int Mp, int Nn) {
  const int i = blockIdx.x * 256 + threadIdx.x;
  if (i >= Nn) return;
  float a = 0.f, b = 0.f;
#pragma unroll
  for (int bnd = 0; bnd < 8; ++bnd) {
    a += sd_part[(size_t)bnd * Mp + i];
    b += ss_part[(size_t)bnd * Mp + i];
  }
  sd[i] = a;
  ss[i] = b;
}

// ---------- GAT softmax + aggregate: 1 wave/dst, bf16x8, 4x unroll ----------
__global__ __launch_bounds__(256) void gat_aggregate_w(
    ushort_t* __restrict__ featb, const ushort_t* __restrict__ hb,
    const float* __restrict__ sd, const float* __restrict__ ss,
    const int* __restrict__ di, const int* __restrict__ si,
    const float* __restrict__ b_att_p, const float* __restrict__ gat_bias,
    const int* __restrict__ cnt, const int* __restrict__ bucket,
    const int* __restrict__ dstlist, const int* __restrict__ dcount,
    int Nn, int E) {
  const int gidx = blockIdx.x * 4 + (threadIdx.x >> 6);
  const int lane = threadIdx.x & 63;
  if (gidx >= *dcount) return;
  const int dst = dstlist[gidx];
  const int deg = cnt[dst];
  const float sdd = sd[dst];
  const float ba = b_att_p[0];
  const size_t o = (size_t)dst * D + lane * 8;
  bf16x8 fv = *reinterpret_cast<const bf16x8*>(&featb[o]);  // hoisted RMW load
  float acc[8] = {};
  if (deg <= 64) {
    const bool valid = lane < deg;
    const int slane = valid ? bucket[(size_t)dst * 64 + lane] : 0;
    const float e = valid ? tanhf(sdd + ss[slane] + ba) : -1e30f;
    float m = e;
#pragma unroll
    for (int off = 32; off > 0; off >>= 1) m = fmaxf(m, __shfl_xor(m, off));
    const float a = valid ? expf(e - m) : 0.f;
    float s = a;
#pragma unroll
    for (int off = 32; off > 0; off >>= 1) s += __shfl_xor(s, off);
    const float w = a * ((s > 0.f) ? 1.f / s : 0.f);  // per-lane alpha
    int k = 0;
    for (; k + 3 < deg; k += 4) {
      const float w0 = __shfl(w, k), w1 = __shfl(w, k + 1);
      const float w2 = __shfl(w, k + 2), w3 = __shfl(w, k + 3);
      const int s0 = __shfl(slane, k), s1 = __shfl(slane, k + 1);
      const int s2 = __shfl(slane, k + 2), s3 = __shfl(slane, k + 3);
      const bf16x8 h0 = *reinterpret_cast<const bf16x8*>(&hb[(size_t)s0 * D + lane * 8]);
      const bf16x8 h1 = *reinterpret_cast<const bf16x8*>(&hb[(size_t)s1 * D + lane * 8]);
      const bf16x8 h2 = *reinterpret_cast<const bf16x8*>(&hb[(size_t)s2 * D + lane * 8]);
      const bf16x8 h3 = *reinterpret_cast<const bf16x8*>(&hb[(size_t)s3 * D + lane * 8]);
#pragma unroll
      for (int qq = 0; qq < 8; ++qq) {
        const float t0 = w0 * bf2f((ushort_t)h0[qq]) + w1 * bf2f((ushort_t)h1[qq]);
        const float t1 = w2 * bf2f((ushort_t)h2[qq]) + w3 * bf2f((ushort_t)h3[qq]);
        acc[qq] += t0 + t1;
      }
    }
    for (; k < deg; ++k) {
      const float wk = __shfl(w, k);
      const int sk = __shfl(slane, k);
      const bf16x8 h0 = *reinterpret_cast<const bf16x8*>(&hb[(size_t)sk * D + lane * 8]);
#pragma unroll
      for (int qq = 0; qq < 8; ++qq) acc[qq] += wk * bf2f((ushort_t)h0[qq]);
    }
  } else {
    // overflow fallback (deg > 64): ballot-scan the raw edge list.
    float m = -1e30f;
    for (int e = lane; e < E; e += 64)
      if (di[e] == dst) m = fmaxf(m, tanhf(sdd + ss[si[e]] + ba));
#pragma unroll
    for (int off = 32; off > 0; off >>= 1) m = fmaxf(m, __shfl_xor(m, off));
    float s = 0.f;
    for (int e = lane; e < E; e += 64)
      if (di[e] == dst) s += expf(tanhf(sdd + ss[si[e]] + ba) - m);
#pragma unroll
    for (int off = 32; off > 0; off >>= 1) s += __shfl_xor(s, off);
    const float inv = (s > 0.f) ? 1.f / s : 0.f;
    for (int base = 0; base < E; base += 64) {
      const int e = base + lane;
      const bool hit = (e < E) && (di[e] == dst);
      unsigned long long mask = __ballot(hit);
      const int sidx = hit ? si[e] : 0;
      const float aval = hit ? expf(tanhf(sdd + ss[sidx] + ba) - m) * inv : 0.f;
      while (mask) {
        const int l = __ffsll((long long)mask) - 1;
        mask &= mask - 1;
        const float wv = __shfl(aval, l);
        const int sk = __shfl(sidx, l);
        const bf16x8 hv = *reinterpret_cast<const bf16x8*>(&hb[(size_t)sk * D + lane * 8]);
#pragma unroll
        for (int qq = 0; qq < 8; ++qq) acc[qq] += wv * bf2f((ushort_t)hv[qq]);
      }
    }
  }
#pragma unroll
  for (int q = 0; q < 8; ++q) {
    const float f = (bf2f((ushort_t)fv[q]) + acc[q] + gat_bias[lane * 8 + q]) * 0.5f;
    fv[q] = (short)f2bf(f);
  }
  *reinterpret_cast<bf16x8*>(&featb[o]) = fv;
}

// ---------- fused head: gather -> Wp -> 2x(2x(GEMM,tanh,LN), res LN) -> logit
// depth-4 register prefetch of W fragments (L2-latency cover).
__global__ __launch_bounds__(1024, 4) void head_fused(
    const ushort_t* __restrict__ featb, const int* __restrict__ tidx,
    const ushort_t* __restrict__ pWp, const float* __restrict__ bp,
    const ushort_t* __restrict__ pDW, const float* __restrict__ dnn_b,
    const float* __restrict__ dnn_g, const float* __restrict__ dnn_be,
    const float* __restrict__ res_g, const float* __restrict__ res_be,
    const float* __restrict__ Wc, const float* __restrict__ bc,
    float* __restrict__ out) {
  __shared__ __align__(16) ushort_t A_lds[16 * 512];
  __shared__ float lsum[16][16], lsq[16][16], meanv[16], rsv[16];
  const int tid = threadIdx.x;
  const int lane = tid & 63;
  const int wave = tid >> 6;      // 0..15
  const int nt0 = wave * 2;       // 2 n-tiles (32 cols) per wave
  const int c15 = lane & 15;
  const int rgrp = lane >> 4;

  {
    const int row = tid >> 6, col8 = tid & 63;
    const int g = tidx[blockIdx.x * 16 + row];
    const bf16x8 v = *reinterpret_cast<const bf16x8*>(&featb[(size_t)g * D + col8 * 8]);
    *reinterpret_cast<bf16x8*>(&A_lds[row * 512 + (col8 ^ (row & 7)) * 8]) = v;
  }
  __syncthreads();

  // GEMM with depth-4 circular register prefetch of W fragments.
  auto do_gemm = [&](const ushort_t* __restrict__ W, f32x4& a0, f32x4& a1) {
    a0 = f32x4{0.f, 0.f, 0.f, 0.f};
    a1 = f32x4{0.f, 0.f, 0.f, 0.f};
    bf16x8 c0[4], c1[4];
#pragma unroll
    for (int d = 0; d < 4; ++d) {
      c0[d] = *reinterpret_cast<const bf16x8*>(
          &W[(((size_t)nt0 * 16 + d) << 9) + lane * 8]);
      c1[d] = *reinterpret_cast<const bf16x8*>(
          &W[(((size_t)(nt0 + 1) * 16 + d) << 9) + lane * 8]);
    }
#pragma unroll
    for (int kt = 0; kt < 16; ++kt) {
      const int slot = kt & 3;
      const bf16x8 w0 = c0[slot];
      const bf16x8 w1 = c1[slot];
      if (kt + 4 < 16) {
        c0[slot] = *reinterpret_cast<const bf16x8*>(
            &W[(((size_t)nt0 * 16 + kt + 4) << 9) + lane * 8]);
        c1[slot] = *reinterpret_cast<const bf16x8*>(
            &W[(((size_t)(nt0 + 1) * 16 + kt + 4) << 9) + lane * 8]);
      }
      const int col8 = kt * 4 + rgrp;
      const bf16x8 af = *reinterpret_cast<const bf16x8*>(
          &A_lds[c15 * 512 + (col8 ^ (c15 & 7)) * 8]);
      a0 = __builtin_amdgcn_mfma_f32_16x16x32_bf16(af, w0, a0, 0, 0, 0);
      a1 = __builtin_amdgcn_mfma_f32_16x16x32_bf16(af, w1, a1, 0, 0, 0);
    }
  };

  auto block_ln = [&](f32x4& v0, f32x4& v1, const float* __restrict__ g,
                      const float* __restrict__ be) {
    float psum[4], psq[4];
#pragma unroll
    for (int r = 0; r < 4; ++r) {
      psum[r] = v0[r] + v1[r];
      psq[r] = v0[r] * v0[r] + v1[r] * v1[r];
    }
#pragma unroll
    for (int off = 8; off > 0; off >>= 1)
#pragma unroll
      for (int r = 0; r < 4; ++r) {
        psum[r] += __shfl_xor(psum[r], off);
        psq[r] += __shfl_xor(psq[r], off);
      }
    if (c15 == 0) {
#pragma unroll
      for (int r = 0; r < 4; ++r) {
        lsum[wave][rgrp * 4 + r] = psum[r];
        lsq[wave][rgrp * 4 + r] = psq[r];
      }
    }
    __syncthreads();
    if (tid < 16) {
      float s = 0.f, qq = 0.f;
#pragma unroll
      for (int w = 0; w < 16; ++w) { s += lsum[w][tid]; qq += lsq[w][tid]; }
      const float mean = s * (1.f / 512.f);
      const float var = qq * (1.f / 512.f) - mean * mean;
      meanv[tid] = mean;
      rsv[tid] = rsqrtf(var + 1e-5f);
    }
    __syncthreads();
    const int col0 = nt0 * 16 + c15;
    const int col1 = (nt0 + 1) * 16 + c15;
    const float g0 = g[col0], b0 = be[col0];
    const float g1 = g[col1], b1 = be[col1];
#pragma unroll
    for (int r = 0; r < 4; ++r) {
      const int row = rgrp * 4 + r;
      v0[r] = (v0[r] - meanv[row]) * rsv[row] * g0 + b0;
      v1[r] = (v1[r] - meanv[row]) * rsv[row] * g1 + b1;
    }
  };

  auto store_A = [&](const f32x4& v0, const f32x4& v1) {
    const int col0 = nt0 * 16 + c15;
    const int col1 = (nt0 + 1) * 16 + c15;
#pragma unroll
    for (int r = 0; r < 4; ++r) {
      const int row = rgrp * 4 + r;
      A_lds[row * 512 + (((col0 >> 3) ^ (row & 7)) << 3) + (col0 & 7)] = f2bf(v0[r]);
      A_lds[row * 512 + (((col1 >> 3) ^ (row & 7)) << 3) + (col1 & 7)] = f2bf(v1[r]);
    }
  };

  f32x4 sc0, sc1, acc0, acc1, ln0, ln1;

  do_gemm(pWp, acc0, acc1);
  {
    const float bv0 = bp[nt0 * 16 + c15];
    const float bv1 = bp[(nt0 + 1) * 16 + c15];
#pragma unroll
    for (int r = 0; r < 4; ++r) { sc0[r] = acc0[r] + bv0; sc1[r] = acc1[r] + bv1; }
  }
  __syncthreads();
  store_A(sc0, sc1);
  __syncthreads();

  for (int rb = 0; rb < 2; ++rb) {
    {
      const int st = rb * 2;
      do_gemm(pDW + (size_t)st * D * D, acc0, acc1);
      const float bv0 = dnn_b[st * D + nt0 * 16 + c15];
      const float bv1 = dnn_b[st * D + (nt0 + 1) * 16 + c15];
#pragma unroll
      for (int r = 0; r < 4; ++r) {
        acc0[r] = tanhf(acc0[r] + bv0);
        acc1[r] = tanhf(acc1[r] + bv1);
      }
      block_ln(acc0, acc1, dnn_g + st * D, dnn_be + st * D);
      store_A(acc0, acc1);
      __syncthreads();
    }
    {
      const int st = rb * 2 + 1;
      do_gemm(pDW + (size_t)st * D * D, ln0, ln1);
      const float bv0 = dnn_b[st * D + nt0 * 16 + c15];
      const float bv1 = dnn_b[st * D + (nt0 + 1) * 16 + c15];
#pragma unroll
      for (int r = 0; r < 4; ++r) {
        ln0[r] = tanhf(ln0[r] + bv0);
        ln1[r] = tanhf(ln1[r] + bv1);
      }
      block_ln(ln0, ln1, dnn_g + st * D, dnn_be + st * D);
    }
#pragma unroll
    for (int r = 0; r < 4; ++r) {
      acc0[r] = tanhf(sc0[r] + ln0[r]);
      acc1[r] = tanhf(sc1[r] + ln1[r]);
    }
    block_ln(acc0, acc1, res_g + rb * D, res_be + rb * D);
    sc0 = acc0;
    sc1 = acc1;
    if (rb == 0) {
      store_A(sc0, sc1);
      __syncthreads();
    }
  }

  float pr[4];
  {
    const float w0 = Wc[nt0 * 16 + c15];
    const float w1 = Wc[(nt0 + 1) * 16 + c15];
#pragma unroll
    for (int r = 0; r < 4; ++r) pr[r] = sc0[r] * w0 + sc1[r] * w1;
  }
#pragma unroll
  for (int off = 8; off > 0; off >>= 1)
#pragma unroll
    for (int r = 0; r < 4; ++r) pr[r] += __shfl_xor(pr[r], off);
  __syncthreads();
  if (c15 == 0) {
#pragma unroll
    for (int r = 0; r < 4; ++r) lsum[wave][rgrp * 4 + r] = pr[r];
  }
  __syncthreads();
  if (tid < 16) {
    float s = 0.f;
#pragma unroll
    for (int w = 0; w < 16; ++w) s += lsum[w][tid];
    out[blockIdx.x * 16 + tid] = 1.f / (1.f + expf(-(s + bc[0])));
  }
}

extern "C" void kernel_launch(void* const* d_in, const int* in_sizes, int n_in,
                              void* d_out, int out_size, void* d_ws, size_t ws_size,
                              hipStream_t stream) {
  (void)n_in; (void)out_size; (void)ws_size;
  const float* node_feat = (const float*)d_in[0];
  const int* edge0 = (const int*)d_in[1];
  const int* edge1 = (const int*)d_in[2];
  const int* tidx = (const int*)d_in[3];
  const float* Wt = (const float*)d_in[4];
  const float* bt = (const float*)d_in[5];
  const float* Wf = (const float*)d_in[6];
  const float* bfp = (const float*)d_in[7];
  const float* w_att = (const float*)d_in[8];
  const float* b_att = (const float*)d_in[9];
  const float* gat_bias = (const float*)d_in[10];
  const float* Wp = (const float*)d_in[11];
  const float* bp = (const float*)d_in[12];
  const float* dnn_W = (const float*)d_in[13];
  const float* dnn_b = (const float*)d_in[14];
  const float* dnn_g = (const float*)d_in[15];
  const float* dnn_be = (const float*)d_in[16];
  const float* res_g = (const float*)d_in[17];
  const float* res_be = (const float*)d_in[18];
  const float* Wc = (const float*)d_in[19];
  const float* bc = (const float*)d_in[20];
  float* out = (float*)d_out;

  const int Nn = in_sizes[0] / D;   // 30000
  const int E = in_sizes[1] / 2;    // 300000
  const int B = in_sizes[3];        // 4096
  const int K_IN = in_sizes[4] / D; // 512 (== D for this model)
  const int Mp = (Nn + 127) / 128 * 128;
  const int N2 = 2 * Nn;

  char* p = (char*)d_ws;
  auto alloc = [&](size_t bytes) -> char* {
    char* r = p;
    p += (bytes + 255) & ~(size_t)255;
    return r;
  };
  ushort_t* featb = (ushort_t*)alloc((size_t)Mp * D * 2);
  ushort_t* hb = (ushort_t*)alloc((size_t)Mp * D * 2);  // also nfb pre-hop
  float* sd = (float*)alloc((size_t)Nn * 4);
  float* ss = (float*)alloc((size_t)Nn * 4);
  float* sd_part = (float*)alloc((size_t)8 * Mp * 4);
  float* ss_part = (float*)alloc((size_t)8 * Mp * 4);
  int* cnt = (int*)alloc((size_t)N2 * 4);
  int* bucket = (int*)alloc((size_t)N2 * 64 * 4);
  int* tflag = (int*)alloc((size_t)Nn * 4);
  int* nflag = (int*)alloc((size_t)Nn * 4);
  int* tlist = (int*)alloc((size_t)B * 4);
  int* nlist = (int*)alloc((size_t)Nn * 4);
  int* counters = (int*)alloc(512);  // [0]=tcount, [64]=ncount
  ushort_t* pAll = (ushort_t*)alloc((size_t)7 * D * D * 2);
  ushort_t* pWt = pAll;
  ushort_t* pWf = pAll + (size_t)D * D;
  ushort_t* pWp = pAll + (size_t)2 * D * D;
  ushort_t* pDWall = pAll + (size_t)3 * D * D;

  dim3 blk(256);

  // ---- one-time packs / converts (K_IN == D for this model) ----
  pack_weight7<<<(7 * D * D + 255) / 256, blk, 0, stream>>>(Wt, Wf, Wp, dnn_W, pAll);
  conv_bf16_pad<<<((size_t)Mp * K_IN / 4 + 255) / 256, blk, 0, stream>>>(
      node_feat, hb /*nfb*/, Nn, Mp, K_IN);

  // ---- init + bucket build + target/N0 sets ----
  init_buffers<<<(N2 + 255) / 256, blk, 0, stream>>>(cnt, tflag, nflag, counters, Nn, N2);
  fill_bucket<<<(E + 255) / 256, blk, 0, stream>>>(edge1, edge0, tidx, tflag,
                                                   cnt, bucket, Nn, E, B);
  flag_srcs<<<(E + 255) / 256, blk, 0, stream>>>(edge0, tflag, nflag, E);
  compact2<<<(Nn + 255) / 256, blk, 0, stream>>>(tflag, nflag, tlist, nlist,
                                                 counters, Nn);

  // ---- feat = node_feat @ Wt + bt ----
  gemm_mfma<<<dim3(4 * (Mp / 128)), dim3(512), 0, stream>>>(
      hb, pWt, bt, featb, nullptr, nullptr, nullptr, Mp, D, K_IN);

  // ---- two GAT hops ----
  const int* hops[2] = {edge1, edge0};
  for (int hp = 0; hp < 2; ++hp) {
    gemm_mfma<<<dim3(4 * (Mp / 128)), dim3(512), 0, stream>>>(
        featb, pWf, bfp, hb, w_att, sd_part, ss_part, Mp, D, D);
    combine_dots<<<(Nn + 255) / 256, blk, 0, stream>>>(sd_part, ss_part, sd, ss, Mp, Nn);
    if (hp == 0) {
      gat_aggregate_w<<<(Nn + 3) / 4, blk, 0, stream>>>(
          featb, hb, sd, ss, hops[hp], hops[hp] + E, b_att, gat_bias,
          cnt + hp * Nn, bucket + (size_t)hp * Nn * 64, nlist, &counters[64], Nn, E);
    } else {
      gat_aggregate_w<<<(B + 3) / 4, blk, 0, stream>>>(
          featb, hb, sd, ss, hops[hp], hops[hp] + E, b_att, gat_bias,
          cnt + hp * Nn, bucket + (size_t)hp * Nn * 64, tlist, &counters[0], Nn, E);
    }
  }

  // ---- fused head ----
  head_fused<<<B / 16, dim3(1024), 0, stream>>>(
      featb, tidx, pWp, bp, pDWall, dnn_b, dnn_g, dnn_be, res_g, res_be,
      Wc, bc, out);
}